// Round 8
// baseline (286.372 us; speedup 1.0000x reference)
//
#include <hip/hip_runtime.h>
#include <math.h>

#define N_NODES 2000
#define NA 16
#define NOBS 64
#define NH 128
#define NE 16000
#define NITERS 8

// ---------------- workspace layout (float offsets) ----------------
#define WS_MSG       0                       // f16-split p weights (mp keeps msgs in regs)
#define WS_FLAGS     300000                  // mp barrier flags: 500*32 + 8*32 ints
#define WS_FLAGS2    340000                  // prefix barrier flags: 563*32 + 8*32 ints
#define WS_Q         512000                  // q[8] (+pad, zeroed each run)
#define WS_SBUF      512016                  // 9 x 32000 uS buffers (u-initialized by umlp)
#define WS_AIDX      800016                  // int[8*2000]
#define WS_W         816016                  // int[16000] wflag
#define WS_PT        832016                  // pT 4,096,000; owner map (4,000,000 ints) aliases
#define WS_GIT       (WS_PT + 4000000)       // gru wihT k-panel 80x384 = 30720 (dead after gru)
#define WS_GHT       (WS_GIT + 30720)        // gru whhT k-panel 128x384 = 49152 (ends < WS_WB)
#define WS_WB        4928016                 // transposed fp32 weights (umlp only)
#define WS_UW0T      (WS_WB + 0)             // 128x256
#define WS_UWCAT     (WS_WB + 32768)         // 128x256  [W0a@h | W0b@h] combined
#define WS_UW1T      (WS_WB + 65536)         // 256x256
#define WS_UW2T      (WS_WB + 131072)        // 256x16   (ping-pong OOB reads land in dead area: benign)
#define WS_CAB       (WS_WB + 241664)        // cab[2000][256] = 512000

// f16 weight offsets (in _Float16 units) within WS_MSG region:
#define F16_W1H 0        // [256][128]
#define F16_W1L 32768
#define F16_W2H 65536    // [256][256]
#define F16_W2L 131072
#define F16_W3H 196608   // [16][256]
#define F16_W3L 200704
#define F16_W4H 204800   // [256][32] (k padded 16->32 with zeros)
#define F16_W4L 212992
// end 221184 f16 = 110592 floats  (< WS_FLAGS: fits inside msg region)

#define NBLK  500        // mp_fused grid
#define NBLK2 563        // gru_umlp grid

typedef _Float16 half8 __attribute__((ext_vector_type(8)));
typedef float f32x4 __attribute__((ext_vector_type(4)));

// ---------------- setup_a: gru panels + owner-init + flag/q zero -------------
// Heavy weight prep (fp32 umlp transposes + f16 p-weights) moved into
// gru_umlp phase-1 idle blocks. Tasks: 16 q + 34528 flags + 79872 gru panels.
__global__ __launch_bounds__(256) void setup_kernel(
    float* __restrict__ ws, const int* __restrict__ edges,
    const float* __restrict__ gwih, const float* __restrict__ gwhh)
{
    if (blockIdx.x >= 448) {
        int e = (blockIdx.x - 448) * 256 + threadIdx.x;
        if (e < NE) {
            int i = edges[2 * e], j = edges[2 * e + 1];
            ((int*)(ws + WS_PT))[i * N_NODES + j] = -1;
        }
        return;
    }
    const int total = 16 + 34528 + 79872;    // 114416 <= 448*256
    int idx = blockIdx.x * 256 + threadIdx.x;
    if (idx >= total) return;
    if (idx < 16) {
        ws[WS_Q + idx] = 0.f;
    } else {
        int t = idx - 16;
        if (t < 16256) {
            ((int*)(ws + WS_FLAGS))[t] = 0;            // mp barrier flags+gen8
        } else if (t < 34528) {
            ((int*)(ws + WS_FLAGS2))[t - 16256] = 0;   // prefix barrier flags+gen8
        } else {
            int q = t - 34528;
            if (q < 30720) {       // gru wihT k-panel
                int k4 = q / 1536, r = q % 1536, g = r >> 2, c = r & 3;
                ws[WS_GIT + q] = gwih[g * 80 + 4 * k4 + c];
            } else {
                int q2 = q - 30720;
                int k4 = q2 / 1536, r = q2 % 1536, g = r >> 2, c = r & 3;
                ws[WS_GHT + q2] = gwhh[g * 128 + 4 * k4 + c];
            }
        }
    }
}

// ---------------- prefix grid barrier (563 blocks x 256 threads) -------------
__device__ __forceinline__ void grid_bar2(int* flags, int gval)
{
    int* gen8 = flags + NBLK2 * 32;
    __syncthreads();
    if (blockIdx.x == 0) {
        for (int i = threadIdx.x; i < NBLK2; i += 256) {
            if (i >= 1) {
                while (__hip_atomic_load(&flags[i * 32], __ATOMIC_RELAXED,
                                         __HIP_MEMORY_SCOPE_AGENT) < gval)
                    __builtin_amdgcn_s_sleep(2);
            }
        }
        __syncthreads();
        if (threadIdx.x < 8)
            __hip_atomic_store(&gen8[threadIdx.x * 32], gval, __ATOMIC_RELAXED,
                               __HIP_MEMORY_SCOPE_AGENT);
    } else {
        if (threadIdx.x == 0) {
            asm volatile("s_waitcnt vmcnt(0)" ::: "memory");
            __hip_atomic_store(&flags[blockIdx.x * 32], gval, __ATOMIC_RELAXED,
                               __HIP_MEMORY_SCOPE_AGENT);
            while (__hip_atomic_load(&gen8[(blockIdx.x & 7) * 32],
                                     __ATOMIC_RELAXED,
                                     __HIP_MEMORY_SCOPE_AGENT) < gval)
                __builtin_amdgcn_s_sleep(2);
        }
        __syncthreads();
    }
}

// ---------------- gru + weight-prep -> bar -> umlp (one kernel) --------------
// P1: blocks 0..249 gru (8 rows each), 250..312 claim, 313..562 weight prep
//     (fp32 umlp transposes via agent write-through stores — consumed in P2
//      cross-XCD; f16 p-weights via normal stores — consumed next kernel).
// P2: blocks 0..249 u-MLP, 250..499 cab, 500..562 resolve.
// h stored via agent write-through (P1 -> P2 cross-XCD).
// LDS 31.2 KB union (gru layout / umlp layout); __launch_bounds__(256,3)
// guarantees >=3 blocks/CU -> 563 co-resident for the barrier.
__global__ __launch_bounds__(256, 3) void gru_umlp_kernel(
    const float* __restrict__ x, const float* __restrict__ pa,
    const float* __restrict__ st, const float* __restrict__ bih,
    const float* __restrict__ bhh, const float* __restrict__ ub0,
    const float* __restrict__ ub1, const float* __restrict__ ub2,
    const int* __restrict__ edges, float* __restrict__ ws,
    float* __restrict__ h_out, float* __restrict__ u_out,
    const float* __restrict__ uW0, const float* __restrict__ uW1,
    const float* __restrict__ uW2, const float* __restrict__ pW0,
    const float* __restrict__ pW1, const float* __restrict__ pW2,
    const float* __restrict__ pW3, const float* __restrict__ pW4)
{
    __shared__ float smem[7808];             // 31232 B
    const int tid = threadIdx.x;
    const int bid = blockIdx.x;
    int* owner   = (int*)(ws + WS_PT);
    int* flags2  = (int*)(ws + WS_FLAGS2);
    const float* wihT = ws + WS_GIT;
    const float* whhT = ws + WS_GHT;

    // ================= P1 =================
    if (bid < 250) {
        // ---- gru: 8 rows ----
        float (*enc)[80]  = (float(*)[80])smem;           // 640
        float (*hp)[128]  = (float(*)[128])(smem + 640);  // 1024
        float (*gi)[384]  = (float(*)[384])(smem + 1664); // 3072
        float (*gh)[384]  = (float(*)[384])(smem + 4736); // 3072
        const int n0 = bid * 8;

        for (int idx = tid; idx < 8 * 80; idx += 256) {
            int r = idx / 80, c = idx % 80;
            enc[r][c] = (c < 64) ? x[(n0 + r) * 64 + c] : pa[(n0 + r) * 16 + (c - 64)];
        }
        for (int idx = tid; idx < 8 * 128; idx += 256) {
            int r = idx >> 7, c = idx & 127;
            hp[r][c] = st[(n0 + r) * 128 + c];
        }
        __syncthreads();

        for (int idx = tid; idx < 8 * 384; idx += 256) {
            int g = idx % 384, r = idx / 384;
            float s1 = bih[g];
            #pragma unroll 5
            for (int k4 = 0; k4 < 20; ++k4) {
                const float4 ev = *(const float4*)&enc[r][4 * k4];
                const float4 wv = *(const float4*)&wihT[k4 * 1536 + g * 4];
                s1 = fmaf(ev.x, wv.x, fmaf(ev.y, wv.y, fmaf(ev.z, wv.z, fmaf(ev.w, wv.w, s1))));
            }
            gi[r][g] = s1;
            float s2 = bhh[g];
            #pragma unroll 8
            for (int k4 = 0; k4 < 32; ++k4) {
                const float4 hv = *(const float4*)&hp[r][4 * k4];
                const float4 wv = *(const float4*)&whhT[k4 * 1536 + g * 4];
                s2 = fmaf(hv.x, wv.x, fmaf(hv.y, wv.y, fmaf(hv.z, wv.z, fmaf(hv.w, wv.w, s2))));
            }
            gh[r][g] = s2;
        }
        __syncthreads();

        for (int idx = tid; idx < 8 * 128; idx += 256) {
            int r = idx >> 7, c = idx & 127;
            float rr = 1.f / (1.f + expf(-(gi[r][c] + gh[r][c])));
            float zz = 1.f / (1.f + expf(-(gi[r][128 + c] + gh[r][128 + c])));
            float nn = tanhf(gi[r][256 + c] + rr * gh[r][256 + c]);
            float hv = (1.f - zz) * nn + zz * hp[r][c];
            // agent write-through: consumed cross-XCD in P2
            __hip_atomic_store(&h_out[(n0 + r) * 128 + c], hv,
                               __ATOMIC_RELAXED, __HIP_MEMORY_SCOPE_AGENT);
        }
    } else if (bid < 313) {
        // ---- claim ----
        int e = (bid - 250) * 256 + tid;
        if (e < NE) {
            int i = edges[2 * e], j = edges[2 * e + 1];
            atomicMax(&owner[i * N_NODES + j], e);
        }
    } else {
        // ---- weight prep: fp32 umlp transposes + f16 p-weight split ----
        _Float16* fw = (_Float16*)ws;        // WS_MSG = 0
        for (int idx = (bid - 313) * 256 + tid; idx < 245760; idx += 250 * 256) {
            if (idx < 135168) {
                int t = idx; float v;
                if (t < 32768) {
                    int k = t / 256, o = t % 256;                 // uW0T
                    v = uW0[o * 128 + k];
                } else if (t < 65536) {
                    int q = t - 32768, k = q / 256, o = q % 256;  // UWCAT: split pW0
                    v = (o < 128) ? pW0[o * 256 + k]
                                  : pW0[(o - 128) * 256 + 128 + k];
                } else if (t < 131072) {
                    int q = t - 65536, k = q / 256, o = q % 256;  // uW1T
                    v = uW1[o * 256 + k];
                } else {
                    int q = t - 131072, k = q / 16, o = q % 16;   // uW2T
                    v = uW2[o * 256 + k];
                }
                // agent write-through: consumed cross-XCD in P2
                __hip_atomic_store(&ws[WS_WB + t], v,
                                   __ATOMIC_RELAXED, __HIP_MEMORY_SCOPE_AGENT);
            } else {
                int q = idx - 135168;        // f16 split (consumed next kernel)
                float v; int hoff, loff;
                if (q < 32768) {                 // pW1: [256][128]
                    v = pW1[q]; hoff = F16_W1H + q; loff = F16_W1L + q;
                } else if (q < 98304) {          // pW2: [256][256]
                    int z = q - 32768; v = pW2[z];
                    hoff = F16_W2H + z; loff = F16_W2L + z;
                } else if (q < 102400) {         // pW3: [16][256]
                    int z = q - 98304; v = pW3[z];
                    hoff = F16_W3H + z; loff = F16_W3L + z;
                } else {                         // pW4: [256][16] -> [256][32] padded
                    int z = q - 102400; int n = z >> 5, kk = z & 31;
                    v = (kk < 16) ? pW4[n * 16 + kk] : 0.f;
                    hoff = F16_W4H + z; loff = F16_W4L + z;
                }
                _Float16 hv = (_Float16)v;
                fw[hoff] = hv;
                fw[loff] = (_Float16)(v - (float)hv);
            }
        }
    }

    grid_bar2(flags2, 1);                    // h, owner, fp32 weights ready

    // ================= P2 =================
    const float* w0t  = ws + WS_UW0T;
    const float* w1t  = ws + WS_UW1T;
    const float* w2t  = ws + WS_UW2T;
    const float* wcat = ws + WS_UWCAT;
    float* Sbuf = ws + WS_SBUF;
    float* cab  = ws + WS_CAB;
    int*   wflag= (int*)(ws + WS_W);

    if (bid >= 500) {
        // ---- resolve ----
        int e = (bid - 500) * 256 + tid;
        if (e < NE) {
            int i = edges[2 * e], j = edges[2 * e + 1];
            wflag[e] = (owner[i * N_NODES + j] == e) ? 1 : 0;
        }
        return;
    }
    float (*A)[128] = (float(*)[128])smem;            // 1024
    float (*B)[256] = (float(*)[256])(smem + 1024);   // 2048
    const bool is_cab = bid >= 250;
    const int n0 = (is_cab ? bid - 250 : bid) * 8;

    __syncthreads();   // all P1 LDS uses done before overwrite
    for (int idx = tid; idx < 8 * 128; idx += 256) {
        int r = idx >> 7, c = idx & 127;
        A[r][c] = h_out[(n0 + r) * 128 + c];
    }
    __syncthreads();

    if (is_cab) {
        const int o = tid;
        const float* wp = wcat + o;
        float wA[4], wB[4];
        #pragma unroll
        for (int c = 0; c < 4; ++c) wA[c] = wp[c * 256];
        float acc[8];
        #pragma unroll
        for (int r = 0; r < 8; ++r) acc[r] = 0.f;
        for (int k4 = 0; k4 < 32; k4 += 2) {
            #pragma unroll
            for (int c = 0; c < 4; ++c) wB[c] = wp[(4 * (k4 + 1) + c) * 256];
            #pragma unroll
            for (int r = 0; r < 8; ++r) {
                const float4 av = *(const float4*)&A[r][4 * k4];
                acc[r] = fmaf(av.x, wA[0], fmaf(av.y, wA[1], fmaf(av.z, wA[2], fmaf(av.w, wA[3], acc[r]))));
            }
            #pragma unroll
            for (int c = 0; c < 4; ++c) wA[c] = wp[(4 * (k4 + 2) + c) * 256]; // benign OOB at last pair
            #pragma unroll
            for (int r = 0; r < 8; ++r) {
                const float4 av = *(const float4*)&A[r][4 * k4 + 4];
                acc[r] = fmaf(av.x, wB[0], fmaf(av.y, wB[1], fmaf(av.z, wB[2], fmaf(av.w, wB[3], acc[r]))));
            }
        }
        #pragma unroll
        for (int r = 0; r < 8; ++r) cab[(n0 + r) * 256 + o] = acc[r];
        return;
    }

    // L0: 128->256 relu, A->B
    {
        const int o = tid;
        const float* wp = w0t + o;
        float wA[4], wB[4];
        #pragma unroll
        for (int c = 0; c < 4; ++c) wA[c] = wp[c * 256];
        float acc[8];
        #pragma unroll
        for (int r = 0; r < 8; ++r) acc[r] = ub0[o];
        for (int k4 = 0; k4 < 32; k4 += 2) {
            #pragma unroll
            for (int c = 0; c < 4; ++c) wB[c] = wp[(4 * (k4 + 1) + c) * 256];
            #pragma unroll
            for (int r = 0; r < 8; ++r) {
                const float4 av = *(const float4*)&A[r][4 * k4];
                acc[r] = fmaf(av.x, wA[0], fmaf(av.y, wA[1], fmaf(av.z, wA[2], fmaf(av.w, wA[3], acc[r]))));
            }
            #pragma unroll
            for (int c = 0; c < 4; ++c) wA[c] = wp[(4 * (k4 + 2) + c) * 256]; // benign OOB at last pair
            #pragma unroll
            for (int r = 0; r < 8; ++r) {
                const float4 av = *(const float4*)&A[r][4 * k4 + 4];
                acc[r] = fmaf(av.x, wB[0], fmaf(av.y, wB[1], fmaf(av.z, wB[2], fmaf(av.w, wB[3], acc[r]))));
            }
        }
        #pragma unroll
        for (int r = 0; r < 8; ++r) B[r][o] = fmaxf(acc[r], 0.f);
    }
    __syncthreads();
    // L1: 256->256 relu, B->B (register staged)
    {
        const int o = tid;
        const float* wp = w1t + o;
        float wA[4], wB[4];
        #pragma unroll
        for (int c = 0; c < 4; ++c) wA[c] = wp[c * 256];
        float acc[8];
        #pragma unroll
        for (int r = 0; r < 8; ++r) acc[r] = ub1[o];
        for (int k4 = 0; k4 < 64; k4 += 2) {
            #pragma unroll
            for (int c = 0; c < 4; ++c) wB[c] = wp[(4 * (k4 + 1) + c) * 256];
            #pragma unroll
            for (int r = 0; r < 8; ++r) {
                const float4 av = *(const float4*)&B[r][4 * k4];
                acc[r] = fmaf(av.x, wA[0], fmaf(av.y, wA[1], fmaf(av.z, wA[2], fmaf(av.w, wA[3], acc[r]))));
            }
            #pragma unroll
            for (int c = 0; c < 4; ++c) wA[c] = wp[(4 * (k4 + 2) + c) * 256]; // benign OOB at last pair
            #pragma unroll
            for (int r = 0; r < 8; ++r) {
                const float4 av = *(const float4*)&B[r][4 * k4 + 4];
                acc[r] = fmaf(av.x, wB[0], fmaf(av.y, wB[1], fmaf(av.z, wB[2], fmaf(av.w, wB[3], acc[r]))));
            }
        }
        __syncthreads();
        #pragma unroll
        for (int r = 0; r < 8; ++r) B[r][o] = fmaxf(acc[r], 0.f);
    }
    __syncthreads();
    // L2: 256->16, /N, no relu (threads 0..127); fan out to u and 9 uS slots
    if (tid < 128) {
        int r = tid >> 4, o = tid & 15;
        float acc = ub2[o];
        for (int k4 = 0; k4 < 64; ++k4) {
            const float4 av = *(const float4*)&B[r][4 * k4];
            acc = fmaf(av.x, w2t[(4 * k4 + 0) * 16 + o],
                  fmaf(av.y, w2t[(4 * k4 + 1) * 16 + o],
                  fmaf(av.z, w2t[(4 * k4 + 2) * 16 + o],
                  fmaf(av.w, w2t[(4 * k4 + 3) * 16 + o], acc))));
        }
        float val = acc * (1.f / N_NODES);
        int idx = (n0 + r) * 16 + o;
        u_out[idx] = val;
        #pragma unroll
        for (int t = 0; t < NITERS + 1; ++t) Sbuf[t * 32000 + idx] = val;
    }
}

// ---------------- p MLP: f16-split MFMA, 32 edges (64 rows) / block ----------
__global__ __launch_bounds__(512, 4) void pmlp_kernel(
    const float* __restrict__ cab, const int* __restrict__ edges,
    const float* __restrict__ b0, const _Float16* __restrict__ fw,
    const float* __restrict__ b1, const float* __restrict__ b2,
    const float* __restrict__ b3, const float* __restrict__ b4,
    float* __restrict__ p_out, float* __restrict__ pT)
{
    __shared__ __align__(16) _Float16 Ah[64][264];
    __shared__ __align__(16) _Float16 Al[64][264];
    __shared__ float C16[64][16];
    __shared__ int fi[64], se[64];

    const int tid  = threadIdx.x;
    const int e0   = blockIdx.x * 32;
    const int wid  = tid >> 6;        // wave 0..7
    const int lane = tid & 63;
    const int lrow = lane & 15;       // A row / B col / C col
    const int lgrp = lane >> 4;       // 0..3
    const int koff = 8 * lgrp;        // k-bijection base (same for A and B)

    if (tid < 32) {
        int i = edges[2 * (e0 + tid)], j = edges[2 * (e0 + tid) + 1];
        fi[2 * tid] = i;     se[2 * tid] = j;       // row 2s  = dir (i,j)
        fi[2 * tid + 1] = j; se[2 * tid + 1] = i;   // row 2s+1 = dir (j,i)
    }
    __syncthreads();

    // L0 (collapsed): relu(ca[fi] + cb[se] + b0) -> f16 hi/lo into Ah/Al[.][0..127]
    {
        const int cl = tid & 127;
        const int rh = tid >> 7;      // 0..3 -> 16 rows each
        const float bb = b0[cl];
        #pragma unroll 4
        for (int r = rh * 16; r < rh * 16 + 16; ++r) {
            float v = cab[fi[r] * 256 + cl] + cab[se[r] * 256 + 128 + cl] + bb;
            v = fmaxf(v, 0.f);
            _Float16 hv = (_Float16)v;
            Ah[r][cl] = hv;
            Al[r][cl] = (_Float16)(v - (float)hv);
        }
    }
    __syncthreads();

    f32x4 acc[4][2];

    // ---- L1: [64x128] @ W1 -> [64x256] relu (MFMA, 96/wave) ----
    #pragma unroll
    for (int mt = 0; mt < 4; ++mt)
        #pragma unroll
        for (int nt = 0; nt < 2; ++nt) acc[mt][nt] = (f32x4){0.f, 0.f, 0.f, 0.f};
    #pragma unroll
    for (int ks = 0; ks < 4; ++ks) {
        half8 ah[4], al[4];
        #pragma unroll
        for (int mt = 0; mt < 4; ++mt) {
            ah[mt] = *(const half8*)&Ah[16 * mt + lrow][32 * ks + koff];
            al[mt] = *(const half8*)&Al[16 * mt + lrow][32 * ks + koff];
        }
        #pragma unroll
        for (int nt = 0; nt < 2; ++nt) {
            const int n = 32 * wid + 16 * nt + lrow;
            half8 bh = *(const half8*)(fw + F16_W1H + n * 128 + 32 * ks + koff);
            half8 bl = *(const half8*)(fw + F16_W1L + n * 128 + 32 * ks + koff);
            #pragma unroll
            for (int mt = 0; mt < 4; ++mt) {
                acc[mt][nt] = __builtin_amdgcn_mfma_f32_16x16x32_f16(ah[mt], bh, acc[mt][nt], 0, 0, 0);
                acc[mt][nt] = __builtin_amdgcn_mfma_f32_16x16x32_f16(ah[mt], bl, acc[mt][nt], 0, 0, 0);
                acc[mt][nt] = __builtin_amdgcn_mfma_f32_16x16x32_f16(al[mt], bh, acc[mt][nt], 0, 0, 0);
            }
        }
    }
    __syncthreads();
    #pragma unroll
    for (int nt = 0; nt < 2; ++nt) {
        const int col = 32 * wid + 16 * nt + lrow;
        const float bv = b1[col];
        #pragma unroll
        for (int mt = 0; mt < 4; ++mt) {
            #pragma unroll
            for (int r = 0; r < 4; ++r) {
                const int row = 16 * mt + 4 * lgrp + r;   // C: row=(lane>>4)*4+reg
                float v = fmaxf(acc[mt][nt][r] + bv, 0.f);
                _Float16 hv = (_Float16)v;
                Ah[row][col] = hv;
                Al[row][col] = (_Float16)(v - (float)hv);
            }
        }
    }
    __syncthreads();

    // ---- L2: [64x256] @ W2 -> [64x256] relu (MFMA, 192/wave) ----
    #pragma unroll
    for (int mt = 0; mt < 4; ++mt)
        #pragma unroll
        for (int nt = 0; nt < 2; ++nt) acc[mt][nt] = (f32x4){0.f, 0.f, 0.f, 0.f};
    for (int ks = 0; ks < 8; ++ks) {
        half8 ah[4], al[4];
        #pragma unroll
        for (int mt = 0; mt < 4; ++mt) {
            ah[mt] = *(const half8*)&Ah[16 * mt + lrow][32 * ks + koff];
            al[mt] = *(const half8*)&Al[16 * mt + lrow][32 * ks + koff];
        }
        #pragma unroll
        for (int nt = 0; nt < 2; ++nt) {
            const int n = 32 * wid + 16 * nt + lrow;
            half8 bh = *(const half8*)(fw + F16_W2H + n * 256 + 32 * ks + koff);
            half8 bl = *(const half8*)(fw + F16_W2L + n * 256 + 32 * ks + koff);
            #pragma unroll
            for (int mt = 0; mt < 4; ++mt) {
                acc[mt][nt] = __builtin_amdgcn_mfma_f32_16x16x32_f16(ah[mt], bh, acc[mt][nt], 0, 0, 0);
                acc[mt][nt] = __builtin_amdgcn_mfma_f32_16x16x32_f16(ah[mt], bl, acc[mt][nt], 0, 0, 0);
                acc[mt][nt] = __builtin_amdgcn_mfma_f32_16x16x32_f16(al[mt], bh, acc[mt][nt], 0, 0, 0);
            }
        }
    }
    __syncthreads();
    #pragma unroll
    for (int nt = 0; nt < 2; ++nt) {
        const int col = 32 * wid + 16 * nt + lrow;
        const float bv = b2[col];
        #pragma unroll
        for (int mt = 0; mt < 4; ++mt) {
            #pragma unroll
            for (int r = 0; r < 4; ++r) {
                const int row = 16 * mt + 4 * lgrp + r;
                float v = fmaxf(acc[mt][nt][r] + bv, 0.f);
                _Float16 hv = (_Float16)v;
                Ah[row][col] = hv;
                Al[row][col] = (_Float16)(v - (float)hv);
            }
        }
    }
    __syncthreads();

    // ---- L3: [64x256] @ W3 -> [64x16] relu (waves 0..3, full K, 24 MFMA) ----
    if (wid < 4) {
        f32x4 acc3 = {0.f, 0.f, 0.f, 0.f};
        #pragma unroll
        for (int ks = 0; ks < 8; ++ks) {
            half8 ah = *(const half8*)&Ah[16 * wid + lrow][32 * ks + koff];
            half8 al = *(const half8*)&Al[16 * wid + lrow][32 * ks + koff];
            half8 bh = *(const half8*)(fw + F16_W3H + lrow * 256 + 32 * ks + koff);
            half8 bl = *(const half8*)(fw + F16_W3L + lrow * 256 + 32 * ks + koff);
            acc3 = __builtin_amdgcn_mfma_f32_16x16x32_f16(ah, bh, acc3, 0, 0, 0);
            acc3 = __builtin_amdgcn_mfma_f32_16x16x32_f16(ah, bl, acc3, 0, 0, 0);
            acc3 = __builtin_amdgcn_mfma_f32_16x16x32_f16(al, bh, acc3, 0, 0, 0);
        }
        const float b3v = b3[lrow];
        #pragma unroll
        for (int r = 0; r < 4; ++r)
            C16[16 * wid + 4 * lgrp + r][lrow] = fmaxf(acc3[r] + b3v, 0.f);
    }
    __syncthreads();

    // ---- L4: [64x16] @ W4 -> [64x256], combine dirs, /E (MFMA, 24/wave) ----
    {
        half8 a4h[4], a4l[4];
        #pragma unroll
        for (int mt = 0; mt < 4; ++mt) {
            half8 hh, ll;
            #pragma unroll
            for (int j = 0; j < 8; ++j) { hh[j] = (_Float16)0.f; ll[j] = (_Float16)0.f; }
            if (lgrp < 2) {   // k = 8*lgrp + j in [0,16); k>=16 lanes carry zeros (padded)
                #pragma unroll
                for (int j = 0; j < 8; ++j) {
                    float v = C16[16 * mt + lrow][8 * lgrp + j];
                    _Float16 hv = (_Float16)v;
                    hh[j] = hv;
                    ll[j] = (_Float16)(v - (float)hv);
                }
            }
            a4h[mt] = hh; a4l[mt] = ll;
        }
        #pragma unroll
        for (int nt = 0; nt < 2; ++nt) {
            const int o = 32 * wid + 16 * nt + lrow;
            const float b4v = b4[o];
            half8 bh = *(const half8*)(fw + F16_W4H + o * 32 + koff);
            half8 bl = *(const half8*)(fw + F16_W4L + o * 32 + koff);
            const int ot = (o & 15) * 16 + (o >> 4);   // pT[e][aj][ai]
            #pragma unroll
            for (int mt = 0; mt < 4; ++mt) {
                f32x4 a4 = {0.f, 0.f, 0.f, 0.f};
                a4 = __builtin_amdgcn_mfma_f32_16x16x32_f16(a4h[mt], bh, a4, 0, 0, 0);
                a4 = __builtin_amdgcn_mfma_f32_16x16x32_f16(a4h[mt], bl, a4, 0, 0, 0);
                a4 = __builtin_amdgcn_mfma_f32_16x16x32_f16(a4l[mt], bh, a4, 0, 0, 0);
                const int s0 = 8 * mt + 2 * lgrp;      // rows (2s0,2s0+1),(2s0+2,2s0+3)
                float pa = (0.5f * (a4[0] + a4[1]) + b4v) * (1.f / NE);
                float pb = (0.5f * (a4[2] + a4[3]) + b4v) * (1.f / NE);
                p_out[(e0 + s0) * 256 + o] = pa;
                p_out[(e0 + s0 + 1) * 256 + o] = pb;
                pT[(e0 + s0) * 256 + ot] = pa;
                pT[(e0 + s0 + 1) * 256 + ot] = pb;
            }
        }
    }
}

// ---------------- contention-free software grid barrier (mp, 512 thr) --------
__device__ __forceinline__ void grid_bar(int* flags, int gval)
{
    int* gen8 = flags + NBLK * 32;
    __syncthreads();
    if (blockIdx.x == 0) {
        const int i = threadIdx.x;
        if (i >= 1 && i < NBLK) {
            while (__hip_atomic_load(&flags[i * 32], __ATOMIC_RELAXED,
                                     __HIP_MEMORY_SCOPE_AGENT) < gval)
                __builtin_amdgcn_s_sleep(2);
        }
        __syncthreads();
        if (i < 8)
            __hip_atomic_store(&gen8[i * 32], gval, __ATOMIC_RELAXED,
                               __HIP_MEMORY_SCOPE_AGENT);
    } else {
        if (threadIdx.x == 0) {
            asm volatile("s_waitcnt vmcnt(0)" ::: "memory");
            __hip_atomic_store(&flags[blockIdx.x * 32], gval, __ATOMIC_RELAXED,
                               __HIP_MEMORY_SCOPE_AGENT);
            while (__hip_atomic_load(&gen8[(blockIdx.x & 7) * 32],
                                     __ATOMIC_RELAXED,
                                     __HIP_MEMORY_SCOPE_AGENT) < gval)
                __builtin_amdgcn_s_sleep(2);
        }
        __syncthreads();
    }
}

// ---------------- fused MP: 8 edge iters -> node-all -> final ----------------
__global__ __launch_bounds__(512, 4) void mp_fused_kernel(
    const float* __restrict__ u, float* __restrict__ Sbuf,
    const float* __restrict__ pT, const float* __restrict__ p,
    const int* __restrict__ edges, const int* __restrict__ wflag,
    int* __restrict__ aidx, float* __restrict__ q,
    float* __restrict__ a_out, float* __restrict__ q_out,
    int* __restrict__ flags)
{
    const int tid = threadIdx.x;
    const int bid = blockIdx.x;
    const int e   = bid * 32 + (tid >> 4);   // 0..15999
    const int L   = tid & 15;

    // ---- persistent per-edge state (registers) ----
    const int gi = edges[2 * e], gj = edges[2 * e + 1];
    const int wf = wflag[e];
    const float4* pt = (const float4*)(pT + e * 256 + L * 16);
    const float4 p0 = pt[0], p1 = pt[1], p2 = pt[2], p3 = pt[3];
    float pv[16] = {p0.x, p0.y, p0.z, p0.w, p1.x, p1.y, p1.z, p1.w,
                    p2.x, p2.y, p2.z, p2.w, p3.x, p3.y, p3.z, p3.w};
    float vmax = -INFINITY;
    #pragma unroll
    for (int a = 0; a < 16; ++a) vmax = fmaxf(vmax, pv[a]);
    float mold_ij = 0.f, mold_ji = 0.f;      // prior mi / mj (replaces msg[])

    for (int t = 0; t < NITERS; ++t) {
        // ---- edge phase, iter t ----
        const float* uSo = Sbuf + t * 32000;
        float* uSn = Sbuf + (t + 1) * 32000;
        const float bi = uSo[gi * 16 + L] - mold_ij;
        const float bj = uSo[gj * 16 + L] - mold_ji;
        float mj = -INFINITY;
        #pragma unroll
        for (int a = 0; a < 16; ++a)
            mj = fmaxf(mj, pv[a] + __shfl(bi, a, 16));
        float mi = vmax + bj;
        float sj = mj, si = mi;
        #pragma unroll
        for (int off = 1; off < 16; off <<= 1) {
            sj += __shfl_xor(sj, off, 16);
            si += __shfl_xor(si, off, 16);
        }
        mj -= sj * (1.f / 16.f);
        mi -= si * (1.f / 16.f);
        mold_ji = mj;
        mold_ij = mi;
        if (wf) {
            atomicAdd(&uSn[gj * 16 + L], mj);
            atomicAdd(&uSn[gi * 16 + L], mi);
        }
        grid_bar(flags, t + 1);              // Sbuf[t+1] complete
    }

    // ---- node-all: blocks 0..287, one t per 36-block group ----
    if (bid < 288) {
        const int t2 = bid / 36;             // 0..7
        const int r2 = (bid % 36) * 512 + tid;
        const float* Sn = Sbuf + (t2 + 1) * 32000;   // = u + S[t2]
        float partial = 0.f;
        if (r2 < N_NODES) {
            int n = r2;
            float bv = Sn[n * 16];
            int best = 0;
            #pragma unroll
            for (int a = 1; a < 16; ++a) {
                float v = Sn[n * 16 + a];
                if (v > bv) { bv = v; best = a; }
            }
            __hip_atomic_store(&aidx[t2 * N_NODES + n], best, __ATOMIC_RELAXED,
                               __HIP_MEMORY_SCOPE_AGENT);   // L2-bypass store
            partial = u[n * 16 + best];
        } else if (r2 < N_NODES + NE) {
            int ee = r2 - N_NODES;
            int ii = edges[2 * ee], jj = edges[2 * ee + 1];
            float bvi = Sn[ii * 16]; int ai = 0;
            #pragma unroll
            for (int a = 1; a < 16; ++a) {
                float v = Sn[ii * 16 + a];
                if (v > bvi) { bvi = v; ai = a; }
            }
            float bvj = Sn[jj * 16]; int aj = 0;
            #pragma unroll
            for (int a = 1; a < 16; ++a) {
                float v = Sn[jj * 16 + a];
                if (v > bvj) { bvj = v; aj = a; }
            }
            partial = p[ee * 256 + ai * 16 + aj];
        }
        #pragma unroll
        for (int off = 1; off < 64; off <<= 1)
            partial += __shfl_xor(partial, off, 64);
        if ((tid & 63) == 0) atomicAdd(&q[t2], partial);
    }
    grid_bar(flags, NITERS + 1);             // all q[t], aidx final

    // ---- final: running strict-> max over iters, one-hot a ----
    const int r = bid * 512 + tid;
    if (r < N_NODES * 16) {
        float cur = 0.f; int best_t = -1;
        #pragma unroll
        for (int t2 = 0; t2 < NITERS; ++t2) {
            float qv = q[t2];
            if (qv > cur) { cur = qv; best_t = t2; }
        }
        int n = r >> 4, c = r & 15;
        float val = 0.f;
        if (best_t >= 0 && aidx[best_t * N_NODES + n] == c) val = 1.f;
        a_out[r] = val;
        if (r == 0) q_out[0] = cur;
    }
}

extern "C" void kernel_launch(void* const* d_in, const int* in_sizes, int n_in,
                              void* d_out, int out_size, void* d_ws, size_t ws_size,
                              hipStream_t stream)
{
    (void)in_sizes; (void)n_in; (void)out_size; (void)ws_size;
    const float* x    = (const float*)d_in[0];
    const float* pa   = (const float*)d_in[1];
    const float* st   = (const float*)d_in[2];
    const int*   edges= (const int*)d_in[3];
    const float* gwih = (const float*)d_in[4];
    const float* gwhh = (const float*)d_in[5];
    const float* gbih = (const float*)d_in[6];
    const float* gbhh = (const float*)d_in[7];
    const float* uW0 = (const float*)d_in[8];  const float* ub0 = (const float*)d_in[9];
    const float* uW1 = (const float*)d_in[10]; const float* ub1 = (const float*)d_in[11];
    const float* uW2 = (const float*)d_in[12]; const float* ub2 = (const float*)d_in[13];
    const float* pW0 = (const float*)d_in[14]; const float* pb0 = (const float*)d_in[15];
    const float* pW1 = (const float*)d_in[16]; const float* pb1 = (const float*)d_in[17];
    const float* pW2 = (const float*)d_in[18]; const float* pb2 = (const float*)d_in[19];
    const float* pW3 = (const float*)d_in[20]; const float* pb3 = (const float*)d_in[21];
    const float* pW4 = (const float*)d_in[22]; const float* pb4 = (const float*)d_in[23];

    float* out   = (float*)d_out;
    float* a_out = out;                 // 32000
    float* q_out = out + 32000;         // 1
    float* u_out = out + 32001;         // 32000
    float* p_out = out + 64001;         // 4,096,000
    float* h_out = out + 4160001;       // 256,000 (state_out)

    float* ws   = (float*)d_ws;
    float* Sbuf = ws + WS_SBUF;
    float* q    = ws + WS_Q;
    int*   flg  = (int*)(ws + WS_FLAGS);
    int*   aidx = (int*)(ws + WS_AIDX);
    int*   wfl  = (int*)(ws + WS_W);
    float* pT   = ws + WS_PT;
    float* cab  = ws + WS_CAB;

    setup_kernel<<<511, 256, 0, stream>>>(ws, edges, gwih, gwhh);
    gru_umlp_kernel<<<NBLK2, 256, 0, stream>>>(x, pa, st, gbih, gbhh,
                                               ub0, ub1, ub2, edges, ws,
                                               h_out, u_out,
                                               uW0, uW1, uW2,
                                               pW0, pW1, pW2, pW3, pW4);
    pmlp_kernel<<<NE / 32, 512, 0, stream>>>(cab, edges, pb0,
                                             (const _Float16*)ws,
                                             pb1, pb2, pb3, pb4, p_out, pT);
    mp_fused_kernel<<<NBLK, 512, 0, stream>>>(u_out, Sbuf, pT, p_out,
                                              edges, wfl, aidx, q,
                                              a_out, q_out, flg);
}

// Round 9
// 266.112 us; speedup vs baseline: 1.0761x; 1.0761x over previous
//
#include <hip/hip_runtime.h>
#include <math.h>

#define N_NODES 2000
#define NA 16
#define NOBS 64
#define NH 128
#define NE 16000
#define NITERS 8

// ---------------- workspace layout (float offsets) ----------------
#define WS_MSG       0                       // f16-split p weights
#define WS_FLAGS     300000                  // barrier flags: 500*32 + 8*32 ints (zeroed each run)
#define WS_Q         512000                  // q[8] (+pad, zeroed each run)
#define WS_SBUF      512016                  // 9 x 32000 uS buffers (u-initialized by umlp)
#define WS_AIDX      800016                  // int[8*2000]
#define WS_W         816016                  // int[16000] wflag
#define WS_PT        832016                  // owner map (4,000,000 ints); pT itself now lives in LDS
#define WS_GIT       (WS_PT + 4000000)       // gru wihT k-panel 80x384 = 30720 (dead after gru)
#define WS_GHT       (WS_GIT + 30720)        // gru whhT k-panel 128x384 = 49152 (ends < WS_WB)
#define WS_WB        4928016                 // transposed fp32 weights (umlp only)
#define WS_UW0T      (WS_WB + 0)             // 128x256
#define WS_UWCAT     (WS_WB + 32768)         // 128x256  [W0a@h | W0b@h] combined
#define WS_UW1T      (WS_WB + 65536)         // 256x256
#define WS_UW2T      (WS_WB + 131072)        // 256x16   (ping-pong OOB reads land in dead area: benign)
#define WS_CAB       (WS_WB + 241664)        // cab[2000][256] = 512000

// f16 weight offsets (in _Float16 units) within WS_MSG region:
#define F16_W1H 0        // [256][128]
#define F16_W1L 32768
#define F16_W2H 65536    // [256][256]
#define F16_W2L 131072
#define F16_W3H 196608   // [16][256]
#define F16_W3L 200704
#define F16_W4H 204800   // [256][32] (k padded 16->32 with zeros)
#define F16_W4L 212992
// end 221184 f16 = 110592 floats  (< WS_FLAGS: fits inside msg region)

#define NBLK 500         // pmlp_mp grid; gen8 lines start at flags + NBLK*32

typedef _Float16 half8 __attribute__((ext_vector_type(8)));
typedef float f32x4 __attribute__((ext_vector_type(4)));

// ---------------- setup (blocks 0..1023) + init_owner (1024..1086) -----------
__global__ __launch_bounds__(256) void setup_kernel(
    float* __restrict__ ws, const int* __restrict__ edges,
    const float* __restrict__ uW0, const float* __restrict__ uW1,
    const float* __restrict__ uW2, const float* __restrict__ pW0,
    const float* __restrict__ pW1, const float* __restrict__ pW2,
    const float* __restrict__ pW3, const float* __restrict__ pW4,
    const float* __restrict__ gwih, const float* __restrict__ gwhh)
{
    if (blockIdx.x >= 1024) {
        int e = (blockIdx.x - 1024) * 256 + threadIdx.x;
        if (e < NE) {
            int i = edges[2 * e], j = edges[2 * e + 1];
            ((int*)(ws + WS_PT))[i * N_NODES + j] = -1;
        }
        return;
    }
    const int total = 341904;
    for (int idx = blockIdx.x * 256 + threadIdx.x; idx < total;
         idx += 1024 * 256) {
        if (idx < 16) {
            ws[WS_Q + idx] = 0.f;            // q[8] + pad
        } else {
            int t = idx - 16;
            if (t < 135168) {
                float v;
                if (t < 32768) {
                    int k = t / 256, o = t % 256;           // uW0T
                    v = uW0[o * 128 + k];
                } else if (t < 65536) {
                    int q = t - 32768, k = q / 256, o = q % 256;  // UWCAT: split pW0
                    v = (o < 128) ? pW0[o * 256 + k]
                                  : pW0[(o - 128) * 256 + 128 + k];
                } else if (t < 131072) {
                    int q = t - 65536, k = q / 256, o = q % 256;  // uW1T
                    v = uW1[o * 256 + k];
                } else {
                    int q = t - 131072, k = q / 16, o = q % 16;   // uW2T
                    v = uW2[o * 256 + k];
                }
                ws[WS_WB + t] = v;
            } else if (t < 215056) {
                int q = t - 135168;
                if (q < 30720) {       // gru wihT k-panel
                    int k4 = q / 1536, r = q % 1536, g = r >> 2, c = r & 3;
                    ws[WS_GIT + q] = gwih[g * 80 + 4 * k4 + c];
                } else if (q < 79872) {
                    int q2 = q - 30720;
                    int k4 = q2 / 1536, r = q2 % 1536, g = r >> 2, c = r & 3;
                    ws[WS_GHT + q2] = gwhh[g * 128 + 4 * k4 + c];
                }
            } else if (t < 325648) {
                // f16 hi/lo split of p-MLP weights (stored [n][k] row-major)
                int q = t - 215056;
                if (q >= 110592) continue;
                _Float16* fw = (_Float16*)ws;   // WS_MSG = 0
                float v; int hoff, loff;
                if (q < 32768) {                 // pW1: [256][128]
                    v = pW1[q]; hoff = F16_W1H + q; loff = F16_W1L + q;
                } else if (q < 98304) {          // pW2: [256][256]
                    int z = q - 32768; v = pW2[z];
                    hoff = F16_W2H + z; loff = F16_W2L + z;
                } else if (q < 102400) {         // pW3: [16][256]
                    int z = q - 98304; v = pW3[z];
                    hoff = F16_W3H + z; loff = F16_W3L + z;
                } else {                         // pW4: [256][16] -> [256][32] padded
                    int z = q - 102400; int n = z >> 5, kk = z & 31;
                    v = (kk < 16) ? pW4[n * 16 + kk] : 0.f;
                    hoff = F16_W4H + z; loff = F16_W4L + z;
                }
                _Float16 hv = (_Float16)v;
                fw[hoff] = hv;
                fw[loff] = (_Float16)(v - (float)hv);
            } else {
                int qf = t - 325648;             // barrier flags + gen8: zero each run
                ((int*)(ws + WS_FLAGS))[qf] = 0;
            }
        }
    }
}

// ---------------- GRU (blocks 0..249) + claim (250..312) ---------------------
__global__ __launch_bounds__(256) void gru_kernel(
    const float* __restrict__ x, const float* __restrict__ pa,
    const float* __restrict__ st, const float* __restrict__ wihT,
    const float* __restrict__ whhT, const float* __restrict__ bih,
    const float* __restrict__ bhh, float* __restrict__ h_out,
    const int* __restrict__ edges, int* __restrict__ owner)
{
    if (blockIdx.x >= 250) {
        int e = (blockIdx.x - 250) * 256 + threadIdx.x;
        if (e < NE) {
            int i = edges[2 * e], j = edges[2 * e + 1];
            atomicMax(&owner[i * N_NODES + j], e);
        }
        return;
    }
    __shared__ float enc[8][80];
    __shared__ float hp[8][128];
    __shared__ float gi[8][384];
    __shared__ float gh[8][384];
    const int tid = threadIdx.x;
    const int n0 = blockIdx.x * 8;

    for (int idx = tid; idx < 8 * 80; idx += 256) {
        int r = idx / 80, c = idx % 80;
        enc[r][c] = (c < 64) ? x[(n0 + r) * 64 + c] : pa[(n0 + r) * 16 + (c - 64)];
    }
    for (int idx = tid; idx < 8 * 128; idx += 256) {
        int r = idx >> 7, c = idx & 127;
        hp[r][c] = st[(n0 + r) * 128 + c];
    }
    __syncthreads();

    for (int idx = tid; idx < 8 * 384; idx += 256) {
        int g = idx % 384, r = idx / 384;
        float s1 = bih[g];
        #pragma unroll 5
        for (int k4 = 0; k4 < 20; ++k4) {
            const float4 ev = *(const float4*)&enc[r][4 * k4];
            const float4 wv = *(const float4*)&wihT[k4 * 1536 + g * 4];
            s1 = fmaf(ev.x, wv.x, fmaf(ev.y, wv.y, fmaf(ev.z, wv.z, fmaf(ev.w, wv.w, s1))));
        }
        gi[r][g] = s1;
        float s2 = bhh[g];
        #pragma unroll 8
        for (int k4 = 0; k4 < 32; ++k4) {
            const float4 hv = *(const float4*)&hp[r][4 * k4];
            const float4 wv = *(const float4*)&whhT[k4 * 1536 + g * 4];
            s2 = fmaf(hv.x, wv.x, fmaf(hv.y, wv.y, fmaf(hv.z, wv.z, fmaf(hv.w, wv.w, s2))));
        }
        gh[r][g] = s2;
    }
    __syncthreads();

    for (int idx = tid; idx < 8 * 128; idx += 256) {
        int r = idx >> 7, c = idx & 127;
        float rr = 1.f / (1.f + expf(-(gi[r][c] + gh[r][c])));
        float zz = 1.f / (1.f + expf(-(gi[r][128 + c] + gh[r][128 + c])));
        float nn = tanhf(gi[r][256 + c] + rr * gh[r][256 + c]);
        h_out[(n0 + r) * 128 + c] = (1.f - zz) * nn + zz * hp[r][c];
    }
}

// ---------------- u MLP (0..249) + cab (250..499) + resolve (500..562) -------
__global__ __launch_bounds__(256) void umlp_kernel(
    const float* __restrict__ h, const float* __restrict__ w0t,
    const float* __restrict__ b0, const float* __restrict__ w1t,
    const float* __restrict__ b1, const float* __restrict__ w2t,
    const float* __restrict__ b2, const float* __restrict__ wcat,
    float* __restrict__ u_out, float* __restrict__ Sbuf,
    float* __restrict__ cab, const int* __restrict__ edges,
    const int* __restrict__ owner, int* __restrict__ wflag)
{
    if (blockIdx.x >= 500) {
        int e = (blockIdx.x - 500) * 256 + threadIdx.x;
        if (e < NE) {
            int i = edges[2 * e], j = edges[2 * e + 1];
            wflag[e] = (owner[i * N_NODES + j] == e) ? 1 : 0;
        }
        return;
    }
    __shared__ float A[8][128];
    __shared__ float B[8][256];
    const int tid = threadIdx.x;
    const bool is_cab = blockIdx.x >= 250;
    const int n0 = (is_cab ? blockIdx.x - 250 : blockIdx.x) * 8;

    for (int idx = tid; idx < 8 * 128; idx += 256) {
        int r = idx >> 7, c = idx & 127;
        A[r][c] = h[(n0 + r) * 128 + c];
    }
    __syncthreads();

    if (is_cab) {
        const int o = tid;
        const float* wp = wcat + o;
        float wA[4], wB[4];
        #pragma unroll
        for (int c = 0; c < 4; ++c) wA[c] = wp[c * 256];
        float acc[8];
        #pragma unroll
        for (int r = 0; r < 8; ++r) acc[r] = 0.f;
        for (int k4 = 0; k4 < 32; k4 += 2) {
            #pragma unroll
            for (int c = 0; c < 4; ++c) wB[c] = wp[(4 * (k4 + 1) + c) * 256];
            #pragma unroll
            for (int r = 0; r < 8; ++r) {
                const float4 av = *(const float4*)&A[r][4 * k4];
                acc[r] = fmaf(av.x, wA[0], fmaf(av.y, wA[1], fmaf(av.z, wA[2], fmaf(av.w, wA[3], acc[r]))));
            }
            #pragma unroll
            for (int c = 0; c < 4; ++c) wA[c] = wp[(4 * (k4 + 2) + c) * 256]; // benign OOB at last pair
            #pragma unroll
            for (int r = 0; r < 8; ++r) {
                const float4 av = *(const float4*)&A[r][4 * k4 + 4];
                acc[r] = fmaf(av.x, wB[0], fmaf(av.y, wB[1], fmaf(av.z, wB[2], fmaf(av.w, wB[3], acc[r]))));
            }
        }
        #pragma unroll
        for (int r = 0; r < 8; ++r) cab[(n0 + r) * 256 + o] = acc[r];
        return;
    }

    // L0: 128->256 relu, A->B
    {
        const int o = tid;
        const float* wp = w0t + o;
        float wA[4], wB[4];
        #pragma unroll
        for (int c = 0; c < 4; ++c) wA[c] = wp[c * 256];
        float acc[8];
        #pragma unroll
        for (int r = 0; r < 8; ++r) acc[r] = b0[o];
        for (int k4 = 0; k4 < 32; k4 += 2) {
            #pragma unroll
            for (int c = 0; c < 4; ++c) wB[c] = wp[(4 * (k4 + 1) + c) * 256];
            #pragma unroll
            for (int r = 0; r < 8; ++r) {
                const float4 av = *(const float4*)&A[r][4 * k4];
                acc[r] = fmaf(av.x, wA[0], fmaf(av.y, wA[1], fmaf(av.z, wA[2], fmaf(av.w, wA[3], acc[r]))));
            }
            #pragma unroll
            for (int c = 0; c < 4; ++c) wA[c] = wp[(4 * (k4 + 2) + c) * 256]; // benign OOB at last pair
            #pragma unroll
            for (int r = 0; r < 8; ++r) {
                const float4 av = *(const float4*)&A[r][4 * k4 + 4];
                acc[r] = fmaf(av.x, wB[0], fmaf(av.y, wB[1], fmaf(av.z, wB[2], fmaf(av.w, wB[3], acc[r]))));
            }
        }
        #pragma unroll
        for (int r = 0; r < 8; ++r) B[r][o] = fmaxf(acc[r], 0.f);
    }
    __syncthreads();
    // L1: 256->256 relu, B->B (register staged)
    {
        const int o = tid;
        const float* wp = w1t + o;
        float wA[4], wB[4];
        #pragma unroll
        for (int c = 0; c < 4; ++c) wA[c] = wp[c * 256];
        float acc[8];
        #pragma unroll
        for (int r = 0; r < 8; ++r) acc[r] = b1[o];
        for (int k4 = 0; k4 < 64; k4 += 2) {
            #pragma unroll
            for (int c = 0; c < 4; ++c) wB[c] = wp[(4 * (k4 + 1) + c) * 256];
            #pragma unroll
            for (int r = 0; r < 8; ++r) {
                const float4 av = *(const float4*)&B[r][4 * k4];
                acc[r] = fmaf(av.x, wA[0], fmaf(av.y, wA[1], fmaf(av.z, wA[2], fmaf(av.w, wA[3], acc[r]))));
            }
            #pragma unroll
            for (int c = 0; c < 4; ++c) wA[c] = wp[(4 * (k4 + 2) + c) * 256]; // benign OOB at last pair
            #pragma unroll
            for (int r = 0; r < 8; ++r) {
                const float4 av = *(const float4*)&B[r][4 * k4 + 4];
                acc[r] = fmaf(av.x, wB[0], fmaf(av.y, wB[1], fmaf(av.z, wB[2], fmaf(av.w, wB[3], acc[r]))));
            }
        }
        __syncthreads();
        #pragma unroll
        for (int r = 0; r < 8; ++r) B[r][o] = fmaxf(acc[r], 0.f);
    }
    __syncthreads();
    // L2: 256->16, /N, no relu (threads 0..127); fan out to u and 9 uS slots
    if (tid < 128) {
        int r = tid >> 4, o = tid & 15;
        float acc = b2[o];
        for (int k4 = 0; k4 < 64; ++k4) {
            const float4 av = *(const float4*)&B[r][4 * k4];
            acc = fmaf(av.x, w2t[(4 * k4 + 0) * 16 + o],
                  fmaf(av.y, w2t[(4 * k4 + 1) * 16 + o],
                  fmaf(av.z, w2t[(4 * k4 + 2) * 16 + o],
                  fmaf(av.w, w2t[(4 * k4 + 3) * 16 + o], acc))));
        }
        float val = acc * (1.f / N_NODES);
        int idx = (n0 + r) * 16 + o;
        u_out[idx] = val;
        #pragma unroll
        for (int t = 0; t < NITERS + 1; ++t) Sbuf[t * 32000 + idx] = val;
    }
}

// ---------------- contention-free software grid barrier (512 thr) ------------
__device__ __forceinline__ void grid_bar(int* flags, int gval)
{
    int* gen8 = flags + NBLK * 32;
    __syncthreads();
    if (blockIdx.x == 0) {
        const int i = threadIdx.x;
        if (i >= 1 && i < NBLK) {
            while (__hip_atomic_load(&flags[i * 32], __ATOMIC_RELAXED,
                                     __HIP_MEMORY_SCOPE_AGENT) < gval)
                __builtin_amdgcn_s_sleep(2);
        }
        __syncthreads();
        if (i < 8)
            __hip_atomic_store(&gen8[i * 32], gval, __ATOMIC_RELAXED,
                               __HIP_MEMORY_SCOPE_AGENT);
    } else {
        if (threadIdx.x == 0) {
            asm volatile("s_waitcnt vmcnt(0)" ::: "memory");
            __hip_atomic_store(&flags[blockIdx.x * 32], gval, __ATOMIC_RELAXED,
                               __HIP_MEMORY_SCOPE_AGENT);
            while (__hip_atomic_load(&gen8[(blockIdx.x & 7) * 32],
                                     __ATOMIC_RELAXED,
                                     __HIP_MEMORY_SCOPE_AGENT) < gval)
                __builtin_amdgcn_s_sleep(2);
        }
        __syncthreads();
    }
}

// ---------------- fused p-MLP + MP: pT passes through LDS --------------------
// Block b's pmlp edges (b*32..+31) == block b's mp edges: pT (33 MB global
// round-trip, mp's dominant FETCH) is replaced by a 32 KB LDS handoff
// (overlaying Ah, dead after L3). p_out stored agent write-through: the node
// phase reads it cross-block/cross-XCD after grid barriers (same pattern as
// aidx). 500 blocks x 512 thr, LDS 72.2 KB -> 2 blocks/CU, 500<=512 resident.
__global__ __launch_bounds__(512, 4) void pmlp_mp_kernel(
    const float* __restrict__ cab, const int* __restrict__ edges,
    const float* __restrict__ b0, const _Float16* __restrict__ fw,
    const float* __restrict__ b1, const float* __restrict__ b2,
    const float* __restrict__ b3, const float* __restrict__ b4,
    float* __restrict__ p_out, const float* __restrict__ u,
    float* __restrict__ Sbuf, const int* __restrict__ wflag,
    int* __restrict__ aidx, float* __restrict__ q,
    float* __restrict__ a_out, float* __restrict__ q_out,
    int* __restrict__ flags)
{
    __shared__ __align__(16) _Float16 Ah[64][264];
    __shared__ __align__(16) _Float16 Al[64][264];
    __shared__ float C16[64][16];
    __shared__ int fi[64], se[64];

    const int tid  = threadIdx.x;
    const int bid  = blockIdx.x;
    const int e0   = bid * 32;
    const int wid  = tid >> 6;        // wave 0..7
    const int lane = tid & 63;
    const int lrow = lane & 15;       // A row / B col / C col
    const int lgrp = lane >> 4;       // 0..3
    const int koff = 8 * lgrp;        // k-bijection base (same for A and B)

    if (tid < 32) {
        int i = edges[2 * (e0 + tid)], j = edges[2 * (e0 + tid) + 1];
        fi[2 * tid] = i;     se[2 * tid] = j;       // row 2s  = dir (i,j)
        fi[2 * tid + 1] = j; se[2 * tid + 1] = i;   // row 2s+1 = dir (j,i)
    }
    __syncthreads();

    // L0 (collapsed): relu(ca[fi] + cb[se] + b0) -> f16 hi/lo into Ah/Al[.][0..127]
    {
        const int cl = tid & 127;
        const int rh = tid >> 7;      // 0..3 -> 16 rows each
        const float bb = b0[cl];
        #pragma unroll 4
        for (int r = rh * 16; r < rh * 16 + 16; ++r) {
            float v = cab[fi[r] * 256 + cl] + cab[se[r] * 256 + 128 + cl] + bb;
            v = fmaxf(v, 0.f);
            _Float16 hv = (_Float16)v;
            Ah[r][cl] = hv;
            Al[r][cl] = (_Float16)(v - (float)hv);
        }
    }
    __syncthreads();

    f32x4 acc[4][2];

    // ---- L1: [64x128] @ W1 -> [64x256] relu (MFMA, 96/wave) ----
    #pragma unroll
    for (int mt = 0; mt < 4; ++mt)
        #pragma unroll
        for (int nt = 0; nt < 2; ++nt) acc[mt][nt] = (f32x4){0.f, 0.f, 0.f, 0.f};
    #pragma unroll
    for (int ks = 0; ks < 4; ++ks) {
        half8 ah[4], al[4];
        #pragma unroll
        for (int mt = 0; mt < 4; ++mt) {
            ah[mt] = *(const half8*)&Ah[16 * mt + lrow][32 * ks + koff];
            al[mt] = *(const half8*)&Al[16 * mt + lrow][32 * ks + koff];
        }
        #pragma unroll
        for (int nt = 0; nt < 2; ++nt) {
            const int n = 32 * wid + 16 * nt + lrow;
            half8 bh = *(const half8*)(fw + F16_W1H + n * 128 + 32 * ks + koff);
            half8 bl = *(const half8*)(fw + F16_W1L + n * 128 + 32 * ks + koff);
            #pragma unroll
            for (int mt = 0; mt < 4; ++mt) {
                acc[mt][nt] = __builtin_amdgcn_mfma_f32_16x16x32_f16(ah[mt], bh, acc[mt][nt], 0, 0, 0);
                acc[mt][nt] = __builtin_amdgcn_mfma_f32_16x16x32_f16(ah[mt], bl, acc[mt][nt], 0, 0, 0);
                acc[mt][nt] = __builtin_amdgcn_mfma_f32_16x16x32_f16(al[mt], bh, acc[mt][nt], 0, 0, 0);
            }
        }
    }
    __syncthreads();
    #pragma unroll
    for (int nt = 0; nt < 2; ++nt) {
        const int col = 32 * wid + 16 * nt + lrow;
        const float bv = b1[col];
        #pragma unroll
        for (int mt = 0; mt < 4; ++mt) {
            #pragma unroll
            for (int r = 0; r < 4; ++r) {
                const int row = 16 * mt + 4 * lgrp + r;   // C: row=(lane>>4)*4+reg
                float v = fmaxf(acc[mt][nt][r] + bv, 0.f);
                _Float16 hv = (_Float16)v;
                Ah[row][col] = hv;
                Al[row][col] = (_Float16)(v - (float)hv);
            }
        }
    }
    __syncthreads();

    // ---- L2: [64x256] @ W2 -> [64x256] relu (MFMA, 192/wave) ----
    #pragma unroll
    for (int mt = 0; mt < 4; ++mt)
        #pragma unroll
        for (int nt = 0; nt < 2; ++nt) acc[mt][nt] = (f32x4){0.f, 0.f, 0.f, 0.f};
    for (int ks = 0; ks < 8; ++ks) {
        half8 ah[4], al[4];
        #pragma unroll
        for (int mt = 0; mt < 4; ++mt) {
            ah[mt] = *(const half8*)&Ah[16 * mt + lrow][32 * ks + koff];
            al[mt] = *(const half8*)&Al[16 * mt + lrow][32 * ks + koff];
        }
        #pragma unroll
        for (int nt = 0; nt < 2; ++nt) {
            const int n = 32 * wid + 16 * nt + lrow;
            half8 bh = *(const half8*)(fw + F16_W2H + n * 256 + 32 * ks + koff);
            half8 bl = *(const half8*)(fw + F16_W2L + n * 256 + 32 * ks + koff);
            #pragma unroll
            for (int mt = 0; mt < 4; ++mt) {
                acc[mt][nt] = __builtin_amdgcn_mfma_f32_16x16x32_f16(ah[mt], bh, acc[mt][nt], 0, 0, 0);
                acc[mt][nt] = __builtin_amdgcn_mfma_f32_16x16x32_f16(ah[mt], bl, acc[mt][nt], 0, 0, 0);
                acc[mt][nt] = __builtin_amdgcn_mfma_f32_16x16x32_f16(al[mt], bh, acc[mt][nt], 0, 0, 0);
            }
        }
    }
    __syncthreads();
    #pragma unroll
    for (int nt = 0; nt < 2; ++nt) {
        const int col = 32 * wid + 16 * nt + lrow;
        const float bv = b2[col];
        #pragma unroll
        for (int mt = 0; mt < 4; ++mt) {
            #pragma unroll
            for (int r = 0; r < 4; ++r) {
                const int row = 16 * mt + 4 * lgrp + r;
                float v = fmaxf(acc[mt][nt][r] + bv, 0.f);
                _Float16 hv = (_Float16)v;
                Ah[row][col] = hv;
                Al[row][col] = (_Float16)(v - (float)hv);
            }
        }
    }
    __syncthreads();

    // ---- L3: [64x256] @ W3 -> [64x16] relu (waves 0..3, full K, 24 MFMA) ----
    if (wid < 4) {
        f32x4 acc3 = {0.f, 0.f, 0.f, 0.f};
        #pragma unroll
        for (int ks = 0; ks < 8; ++ks) {
            half8 ah = *(const half8*)&Ah[16 * wid + lrow][32 * ks + koff];
            half8 al = *(const half8*)&Al[16 * wid + lrow][32 * ks + koff];
            half8 bh = *(const half8*)(fw + F16_W3H + lrow * 256 + 32 * ks + koff);
            half8 bl = *(const half8*)(fw + F16_W3L + lrow * 256 + 32 * ks + koff);
            acc3 = __builtin_amdgcn_mfma_f32_16x16x32_f16(ah, bh, acc3, 0, 0, 0);
            acc3 = __builtin_amdgcn_mfma_f32_16x16x32_f16(ah, bl, acc3, 0, 0, 0);
            acc3 = __builtin_amdgcn_mfma_f32_16x16x32_f16(al, bh, acc3, 0, 0, 0);
        }
        const float b3v = b3[lrow];
        #pragma unroll
        for (int r = 0; r < 4; ++r)
            C16[16 * wid + 4 * lgrp + r][lrow] = fmaxf(acc3[r] + b3v, 0.f);
    }
    __syncthreads();   // Ah/Al dead from here: pTl overlays Ah

    float* pTl = (float*)Ah;   // [32][256] floats = 32 KB (< Ah's 33.8 KB)

    // ---- L4: [64x16] @ W4 -> [64x256]; p_out agent-store; pT -> LDS ----
    {
        half8 a4h[4], a4l[4];
        #pragma unroll
        for (int mt = 0; mt < 4; ++mt) {
            half8 hh, ll;
            #pragma unroll
            for (int j = 0; j < 8; ++j) { hh[j] = (_Float16)0.f; ll[j] = (_Float16)0.f; }
            if (lgrp < 2) {   // k = 8*lgrp + j in [0,16); k>=16 lanes carry zeros (padded)
                #pragma unroll
                for (int j = 0; j < 8; ++j) {
                    float v = C16[16 * mt + lrow][8 * lgrp + j];
                    _Float16 hv = (_Float16)v;
                    hh[j] = hv;
                    ll[j] = (_Float16)(v - (float)hv);
                }
            }
            a4h[mt] = hh; a4l[mt] = ll;
        }
        #pragma unroll
        for (int nt = 0; nt < 2; ++nt) {
            const int o = 32 * wid + 16 * nt + lrow;
            const float b4v = b4[o];
            half8 bh = *(const half8*)(fw + F16_W4H + o * 32 + koff);
            half8 bl = *(const half8*)(fw + F16_W4L + o * 32 + koff);
            const int ot = (o & 15) * 16 + (o >> 4);   // pT[e][aj][ai]
            #pragma unroll
            for (int mt = 0; mt < 4; ++mt) {
                f32x4 a4 = {0.f, 0.f, 0.f, 0.f};
                a4 = __builtin_amdgcn_mfma_f32_16x16x32_f16(a4h[mt], bh, a4, 0, 0, 0);
                a4 = __builtin_amdgcn_mfma_f32_16x16x32_f16(a4h[mt], bl, a4, 0, 0, 0);
                a4 = __builtin_amdgcn_mfma_f32_16x16x32_f16(a4l[mt], bh, a4, 0, 0, 0);
                const int s0 = 8 * mt + 2 * lgrp;      // rows (2s0,2s0+1),(2s0+2,2s0+3)
                float pa = (0.5f * (a4[0] + a4[1]) + b4v) * (1.f / NE);
                float pb = (0.5f * (a4[2] + a4[3]) + b4v) * (1.f / NE);
                // agent write-through: node phase reads cross-XCD post-barrier
                __hip_atomic_store(&p_out[(e0 + s0) * 256 + o], pa,
                                   __ATOMIC_RELAXED, __HIP_MEMORY_SCOPE_AGENT);
                __hip_atomic_store(&p_out[(e0 + s0 + 1) * 256 + o], pb,
                                   __ATOMIC_RELAXED, __HIP_MEMORY_SCOPE_AGENT);
                pTl[s0 * 256 + ot] = pa;               // block-local handoff
                pTl[(s0 + 1) * 256 + ot] = pb;
            }
        }
    }
    __syncthreads();

    // ================= MP phase =================
    const int g = tid >> 4;                  // edge slot 0..31; e = e0 + g
    const int L = tid & 15;
    const int e = e0 + g;
    const int gi = edges[2 * e], gj = edges[2 * e + 1];
    const int wf = wflag[e];
    float pv[16];
    #pragma unroll
    for (int a4i = 0; a4i < 4; ++a4i) {
        float4 v = *(const float4*)&pTl[g * 256 + L * 16 + 4 * a4i];
        pv[4 * a4i + 0] = v.x; pv[4 * a4i + 1] = v.y;
        pv[4 * a4i + 2] = v.z; pv[4 * a4i + 3] = v.w;
    }
    float vmax = -INFINITY;
    #pragma unroll
    for (int a = 0; a < 16; ++a) vmax = fmaxf(vmax, pv[a]);
    float mold_ij = 0.f, mold_ji = 0.f;      // running mi / mj (in regs)

    for (int t = 0; t < NITERS; ++t) {
        // ---- edge phase, iter t ----
        const float* uSo = Sbuf + t * 32000;
        float* uSn = Sbuf + (t + 1) * 32000;
        const float bi = uSo[gi * 16 + L] - mold_ij;
        const float bj = uSo[gj * 16 + L] - mold_ji;
        float mj = -INFINITY;
        #pragma unroll
        for (int a = 0; a < 16; ++a)
            mj = fmaxf(mj, pv[a] + __shfl(bi, a, 16));
        float mi = vmax + bj;
        float sj = mj, si = mi;
        #pragma unroll
        for (int off = 1; off < 16; off <<= 1) {
            sj += __shfl_xor(sj, off, 16);
            si += __shfl_xor(si, off, 16);
        }
        mj -= sj * (1.f / 16.f);
        mi -= si * (1.f / 16.f);
        mold_ji = mj;
        mold_ij = mi;
        if (wf) {
            atomicAdd(&uSn[gj * 16 + L], mj);
            atomicAdd(&uSn[gi * 16 + L], mi);
        }
        grid_bar(flags, t + 1);              // Sbuf[t+1] complete
    }

    // ---- node-all: blocks 0..287, one t per 36-block group ----
    if (bid < 288) {
        const int t2 = bid / 36;             // 0..7
        const int r2 = (bid % 36) * 512 + tid;
        const float* Sn = Sbuf + (t2 + 1) * 32000;   // = u + S[t2]
        float partial = 0.f;
        if (r2 < N_NODES) {
            int n = r2;
            float bv = Sn[n * 16];
            int best = 0;
            #pragma unroll
            for (int a = 1; a < 16; ++a) {
                float v = Sn[n * 16 + a];
                if (v > bv) { bv = v; best = a; }
            }
            __hip_atomic_store(&aidx[t2 * N_NODES + n], best, __ATOMIC_RELAXED,
                               __HIP_MEMORY_SCOPE_AGENT);   // L2-bypass store
            partial = u[n * 16 + best];
        } else if (r2 < N_NODES + NE) {
            int ee = r2 - N_NODES;
            int ii = edges[2 * ee], jj = edges[2 * ee + 1];
            float bvi = Sn[ii * 16]; int ai = 0;
            #pragma unroll
            for (int a = 1; a < 16; ++a) {
                float v = Sn[ii * 16 + a];
                if (v > bvi) { bvi = v; ai = a; }
            }
            float bvj = Sn[jj * 16]; int aj = 0;
            #pragma unroll
            for (int a = 1; a < 16; ++a) {
                float v = Sn[jj * 16 + a];
                if (v > bvj) { bvj = v; aj = a; }
            }
            partial = p_out[ee * 256 + ai * 16 + aj];
        }
        #pragma unroll
        for (int off = 1; off < 64; off <<= 1)
            partial += __shfl_xor(partial, off, 64);
        if ((tid & 63) == 0) atomicAdd(&q[t2], partial);
    }
    grid_bar(flags, NITERS + 1);             // all q[t], aidx final

    // ---- final: running strict-> max over iters, one-hot a ----
    const int r = bid * 512 + tid;
    if (r < N_NODES * 16) {
        float cur = 0.f; int best_t = -1;
        #pragma unroll
        for (int t2 = 0; t2 < NITERS; ++t2) {
            float qv = q[t2];
            if (qv > cur) { cur = qv; best_t = t2; }
        }
        int n = r >> 4, c = r & 15;
        float val = 0.f;
        if (best_t >= 0 && aidx[best_t * N_NODES + n] == c) val = 1.f;
        a_out[r] = val;
        if (r == 0) q_out[0] = cur;
    }
}

extern "C" void kernel_launch(void* const* d_in, const int* in_sizes, int n_in,
                              void* d_out, int out_size, void* d_ws, size_t ws_size,
                              hipStream_t stream)
{
    (void)in_sizes; (void)n_in; (void)out_size; (void)ws_size;
    const float* x    = (const float*)d_in[0];
    const float* pa   = (const float*)d_in[1];
    const float* st   = (const float*)d_in[2];
    const int*   edges= (const int*)d_in[3];
    const float* gwih = (const float*)d_in[4];
    const float* gwhh = (const float*)d_in[5];
    const float* gbih = (const float*)d_in[6];
    const float* gbhh = (const float*)d_in[7];
    const float* uW0 = (const float*)d_in[8];  const float* ub0 = (const float*)d_in[9];
    const float* uW1 = (const float*)d_in[10]; const float* ub1 = (const float*)d_in[11];
    const float* uW2 = (const float*)d_in[12]; const float* ub2 = (const float*)d_in[13];
    const float* pW0 = (const float*)d_in[14]; const float* pb0 = (const float*)d_in[15];
    const float* pW1 = (const float*)d_in[16]; const float* pb1 = (const float*)d_in[17];
    const float* pW2 = (const float*)d_in[18]; const float* pb2 = (const float*)d_in[19];
    const float* pW3 = (const float*)d_in[20]; const float* pb3 = (const float*)d_in[21];
    const float* pW4 = (const float*)d_in[22]; const float* pb4 = (const float*)d_in[23];

    float* out   = (float*)d_out;
    float* a_out = out;                 // 32000
    float* q_out = out + 32000;         // 1
    float* u_out = out + 32001;         // 32000
    float* p_out = out + 64001;         // 4,096,000
    float* h_out = out + 4160001;       // 256,000 (state_out)

    float* ws   = (float*)d_ws;
    float* Sbuf = ws + WS_SBUF;
    float* q    = ws + WS_Q;
    int*   flg  = (int*)(ws + WS_FLAGS);
    int*   aidx = (int*)(ws + WS_AIDX);
    int*   wfl  = (int*)(ws + WS_W);
    float* cab  = ws + WS_CAB;
    int*   owner= (int*)(ws + WS_PT);

    setup_kernel<<<1087, 256, 0, stream>>>(ws, edges, uW0, uW1, uW2,
                                           pW0, pW1, pW2, pW3, pW4, gwih, gwhh);
    gru_kernel<<<313, 256, 0, stream>>>(x, pa, st, ws + WS_GIT, ws + WS_GHT,
                                        gbih, gbhh, h_out, edges, owner);
    umlp_kernel<<<563, 256, 0, stream>>>(h_out, ws + WS_UW0T, ub0,
                                         ws + WS_UW1T, ub1, ws + WS_UW2T, ub2,
                                         ws + WS_UWCAT, u_out, Sbuf, cab,
                                         edges, owner, wfl);
    pmlp_mp_kernel<<<NBLK, 512, 0, stream>>>(cab, edges, pb0,
                                             (const _Float16*)ws,
                                             pb1, pb2, pb3, pb4, p_out,
                                             u_out, Sbuf, wfl, aidx, q,
                                             a_out, q_out, flg);
}

// Round 10
// 261.525 us; speedup vs baseline: 1.0950x; 1.0175x over previous
//
#include <hip/hip_runtime.h>
#include <math.h>

#define N_NODES 2000
#define NA 16
#define NOBS 64
#define NH 128
#define NE 16000
#define NITERS 8

// ---------------- workspace layout (float offsets) ----------------
#define WS_MSG       0                       // f16-split p weights
#define WS_FLAGS     300000                  // barrier flags: 500*32 + 8*32 ints (zeroed each run)
#define WS_Q         512000                  // q[8] (+pad, zeroed each run)
#define WS_SBUF      512016                  // 9 x 32000 uS buffers (agent-stored by P_u)
#define WS_AIDX      800016                  // int[8*2000]
#define WS_W         816016                  // (unused now; wflag is block-local LDS)
#define WS_PT        832016                  // owner map (4,000,000 ints)
#define WS_GIT       (WS_PT + 4000000)       // gru wihT k-panel 80x384 = 30720
#define WS_GHT       (WS_GIT + 30720)        // gru whhT k-panel 128x384 = 49152
#define WS_WB        4928016                 // transposed fp32 weights (umlp)
#define WS_UW0T      (WS_WB + 0)             // 128x256
#define WS_UWCAT     (WS_WB + 32768)         // 128x256  [W0a@h | W0b@h] combined
#define WS_UW1T      (WS_WB + 65536)         // 256x256
#define WS_UW2T      (WS_WB + 131072)        // 256x16
#define WS_CAB       (WS_WB + 241664)        // cab[2000][256] = 512000

// f16 weight offsets (in _Float16 units) within WS_MSG region:
#define F16_W1H 0        // [256][128]
#define F16_W1L 32768
#define F16_W2H 65536    // [256][256]
#define F16_W2L 131072
#define F16_W3H 196608   // [16][256]
#define F16_W3L 200704
#define F16_W4H 204800   // [256][32] (k padded 16->32 with zeros)
#define F16_W4L 212992

#define NBLK 500         // mega grid; gen8 lines start at flags + NBLK*32

typedef _Float16 half8 __attribute__((ext_vector_type(8)));
typedef float f32x4 __attribute__((ext_vector_type(4)));

#define AGST(p, v) __hip_atomic_store((p), (v), __ATOMIC_RELAXED, __HIP_MEMORY_SCOPE_AGENT)

// ---------------- setup (blocks 0..1023) + init_owner (1024..1086) -----------
__global__ __launch_bounds__(256) void setup_kernel(
    float* __restrict__ ws, const int* __restrict__ edges,
    const float* __restrict__ uW0, const float* __restrict__ uW1,
    const float* __restrict__ uW2, const float* __restrict__ pW0,
    const float* __restrict__ pW1, const float* __restrict__ pW2,
    const float* __restrict__ pW3, const float* __restrict__ pW4,
    const float* __restrict__ gwih, const float* __restrict__ gwhh)
{
    if (blockIdx.x >= 1024) {
        int e = (blockIdx.x - 1024) * 256 + threadIdx.x;
        if (e < NE) {
            int i = edges[2 * e], j = edges[2 * e + 1];
            ((int*)(ws + WS_PT))[i * N_NODES + j] = -1;
        }
        return;
    }
    const int total = 341904;
    for (int idx = blockIdx.x * 256 + threadIdx.x; idx < total;
         idx += 1024 * 256) {
        if (idx < 16) {
            ws[WS_Q + idx] = 0.f;            // q[8] + pad
        } else {
            int t = idx - 16;
            if (t < 135168) {
                float v;
                if (t < 32768) {
                    int k = t / 256, o = t % 256;           // uW0T
                    v = uW0[o * 128 + k];
                } else if (t < 65536) {
                    int q = t - 32768, k = q / 256, o = q % 256;  // UWCAT: split pW0
                    v = (o < 128) ? pW0[o * 256 + k]
                                  : pW0[(o - 128) * 256 + 128 + k];
                } else if (t < 131072) {
                    int q = t - 65536, k = q / 256, o = q % 256;  // uW1T
                    v = uW1[o * 256 + k];
                } else {
                    int q = t - 131072, k = q / 16, o = q % 16;   // uW2T
                    v = uW2[o * 256 + k];
                }
                ws[WS_WB + t] = v;
            } else if (t < 215056) {
                int q = t - 135168;
                if (q < 30720) {       // gru wihT k-panel
                    int k4 = q / 1536, r = q % 1536, g = r >> 2, c = r & 3;
                    ws[WS_GIT + q] = gwih[g * 80 + 4 * k4 + c];
                } else if (q < 79872) {
                    int q2 = q - 30720;
                    int k4 = q2 / 1536, r = q2 % 1536, g = r >> 2, c = r & 3;
                    ws[WS_GHT + q2] = gwhh[g * 128 + 4 * k4 + c];
                }
            } else if (t < 325648) {
                // f16 hi/lo split of p-MLP weights (stored [n][k] row-major)
                int q = t - 215056;
                if (q >= 110592) continue;
                _Float16* fw = (_Float16*)ws;   // WS_MSG = 0
                float v; int hoff, loff;
                if (q < 32768) {                 // pW1: [256][128]
                    v = pW1[q]; hoff = F16_W1H + q; loff = F16_W1L + q;
                } else if (q < 98304) {          // pW2: [256][256]
                    int z = q - 32768; v = pW2[z];
                    hoff = F16_W2H + z; loff = F16_W2L + z;
                } else if (q < 102400) {         // pW3: [16][256]
                    int z = q - 98304; v = pW3[z];
                    hoff = F16_W3H + z; loff = F16_W3L + z;
                } else {                         // pW4: [256][16] -> [256][32] padded
                    int z = q - 102400; int n = z >> 5, kk = z & 31;
                    v = (kk < 16) ? pW4[n * 16 + kk] : 0.f;
                    hoff = F16_W4H + z; loff = F16_W4L + z;
                }
                _Float16 hv = (_Float16)v;
                fw[hoff] = hv;
                fw[loff] = (_Float16)(v - (float)hv);
            } else {
                int qf = t - 325648;             // barrier flags + gen8: zero each run
                ((int*)(ws + WS_FLAGS))[qf] = 0;
            }
        }
    }
}

// ---------------- contention-free software grid barrier (512 thr) ------------
__device__ __forceinline__ void grid_bar(int* flags, int gval)
{
    int* gen8 = flags + NBLK * 32;
    __syncthreads();   // compiler drains vmcnt before s_barrier: all this
                       // block's stores/atomics complete before arrival
    if (blockIdx.x == 0) {
        const int i = threadIdx.x;
        if (i >= 1 && i < NBLK) {
            while (__hip_atomic_load(&flags[i * 32], __ATOMIC_RELAXED,
                                     __HIP_MEMORY_SCOPE_AGENT) < gval)
                __builtin_amdgcn_s_sleep(2);
        }
        __syncthreads();
        if (i < 8)
            __hip_atomic_store(&gen8[i * 32], gval, __ATOMIC_RELAXED,
                               __HIP_MEMORY_SCOPE_AGENT);
    } else {
        if (threadIdx.x == 0) {
            asm volatile("s_waitcnt vmcnt(0)" ::: "memory");
            __hip_atomic_store(&flags[blockIdx.x * 32], gval, __ATOMIC_RELAXED,
                               __HIP_MEMORY_SCOPE_AGENT);
            while (__hip_atomic_load(&gen8[(blockIdx.x & 7) * 32],
                                     __ATOMIC_RELAXED,
                                     __HIP_MEMORY_SCOPE_AGENT) < gval)
                __builtin_amdgcn_s_sleep(2);
        }
        __syncthreads();
    }
}

// ---------------- mega: gru -> u/cab/resolve -> pmlp -> MP (one kernel) ------
// All phases balanced across 500 blocks x 512 threads (2 blocks/CU, 16
// waves/CU). Block-local handoffs: h (gru->umlp via LDS A), wflag (resolve->MP
// via LDS), pT (pmlp->MP via LDS). Cross-block data (cab, u, Sbuf init, p_out,
// aidx) uses agent write-through stores + grid barrier (validated r8/r9).
__global__ __launch_bounds__(512, 4) void mega_kernel(
    const float* __restrict__ x, const float* __restrict__ pa,
    const float* __restrict__ st, const float* __restrict__ bih,
    const float* __restrict__ bhh, const float* __restrict__ ub0,
    const float* __restrict__ ub1, const float* __restrict__ ub2,
    const float* __restrict__ b0, const float* __restrict__ b1,
    const float* __restrict__ b2, const float* __restrict__ b3,
    const float* __restrict__ b4, const int* __restrict__ edges,
    float* __restrict__ ws, float* __restrict__ h_out,
    float* __restrict__ u_out, float* __restrict__ p_out,
    float* __restrict__ a_out, float* __restrict__ q_out)
{
    __shared__ __align__(16) _Float16 Ah[64][264];
    __shared__ __align__(16) _Float16 Al[64][264];
    __shared__ float C16[64][16];
    __shared__ int fi[64], se[64];
    __shared__ int wfl_l[32];

    const int tid  = threadIdx.x;
    const int bid  = blockIdx.x;
    const int e0   = bid * 32;
    const int wid  = tid >> 6;        // wave 0..7
    const int lane = tid & 63;
    const int lrow = lane & 15;
    const int lgrp = lane >> 4;
    const int koff = 8 * lgrp;

    float* sm = (float*)&Ah[0][0];    // scratch union inside Ah (8448 floats)
    int*   flags = (int*)(ws + WS_FLAGS);
    int*   owner = (int*)(ws + WS_PT);
    const _Float16* fw = (const _Float16*)ws;
    float* Sbuf = ws + WS_SBUF;
    float* q    = ws + WS_Q;
    int*   aidx = (int*)(ws + WS_AIDX);
    float* cab  = ws + WS_CAB;

    if (tid < 32) {
        int i = edges[2 * (e0 + tid)], j = edges[2 * (e0 + tid) + 1];
        fi[2 * tid] = i;     se[2 * tid] = j;
        fi[2 * tid + 1] = j; se[2 * tid + 1] = i;
    }

    // ================= P_gru: 4 nodes/block + claim =================
    {
        float* enc = sm;              // [4][80]
        float* hp  = sm + 320;        // [4][128]
        float* gi  = sm + 832;        // [4][384]
        float* gh  = sm + 2368;       // [4][384]
        float* A   = sm + 3904;       // [4][128] persists into P_u
        const float* wihT = ws + WS_GIT;
        const float* whhT = ws + WS_GHT;
        const int n0 = bid * 4;

        if (tid < 320) {
            int r = tid / 80, c = tid % 80;
            enc[r * 80 + c] = (c < 64) ? x[(n0 + r) * 64 + c]
                                       : pa[(n0 + r) * 16 + (c - 64)];
        }
        {
            int r = tid >> 7, c = tid & 127;
            hp[r * 128 + c] = st[(n0 + r) * 128 + c];
        }
        __syncthreads();

        #pragma unroll
        for (int ii = 0; ii < 3; ++ii) {
            int idx = ii * 512 + tid;          // 0..1535
            int g = idx % 384, r = idx / 384;
            float s1 = bih[g];
            #pragma unroll 5
            for (int k4 = 0; k4 < 20; ++k4) {
                const float4 ev = *(const float4*)&enc[r * 80 + 4 * k4];
                const float4 wv = *(const float4*)&wihT[k4 * 1536 + g * 4];
                s1 = fmaf(ev.x, wv.x, fmaf(ev.y, wv.y, fmaf(ev.z, wv.z, fmaf(ev.w, wv.w, s1))));
            }
            gi[r * 384 + g] = s1;
            float s2 = bhh[g];
            #pragma unroll 8
            for (int k4 = 0; k4 < 32; ++k4) {
                const float4 hv = *(const float4*)&hp[r * 128 + 4 * k4];
                const float4 wv = *(const float4*)&whhT[k4 * 1536 + g * 4];
                s2 = fmaf(hv.x, wv.x, fmaf(hv.y, wv.y, fmaf(hv.z, wv.z, fmaf(hv.w, wv.w, s2))));
            }
            gh[r * 384 + g] = s2;
        }
        __syncthreads();

        {
            int r = tid >> 7, c = tid & 127;
            float rr = 1.f / (1.f + expf(-(gi[r * 384 + c] + gh[r * 384 + c])));
            float zz = 1.f / (1.f + expf(-(gi[r * 384 + 128 + c] + gh[r * 384 + 128 + c])));
            float nn = tanhf(gi[r * 384 + 256 + c] + rr * gh[r * 384 + 256 + c]);
            float hv = (1.f - zz) * nn + zz * hp[r * 128 + c];
            A[r * 128 + c] = hv;                  // block-local handoff
            h_out[(n0 + r) * 128 + c] = hv;       // state_out output
        }
        if (tid < 32) {
            int e = e0 + tid;
            atomicMax(&owner[fi[2 * tid] * N_NODES + se[2 * tid]], e);
        }
    }
    grid_bar(flags, 1);                  // owner final (h is block-local)

    // ================= P_u: u-MLP + cab + resolve (4 nodes/block) ===========
    {
        float* A = sm + 3904;            // h rows (from P_gru, same block)
        float* B = sm + 4416;            // [4][256]
        const int n0 = bid * 4;
        const int o  = tid & 255;
        const int r0 = (tid >> 8) * 2;   // rows r0, r0+1

        // L0: 128->256 relu, A->B
        {
            const float* wp = ws + WS_UW0T + o;
            float a0 = ub0[o], a1 = a0;
            for (int k4 = 0; k4 < 32; ++k4) {
                float w0 = wp[(4 * k4 + 0) * 256], w1 = wp[(4 * k4 + 1) * 256];
                float w2 = wp[(4 * k4 + 2) * 256], w3 = wp[(4 * k4 + 3) * 256];
                const float4 v0 = *(const float4*)&A[r0 * 128 + 4 * k4];
                const float4 v1 = *(const float4*)&A[(r0 + 1) * 128 + 4 * k4];
                a0 = fmaf(v0.x, w0, fmaf(v0.y, w1, fmaf(v0.z, w2, fmaf(v0.w, w3, a0))));
                a1 = fmaf(v1.x, w0, fmaf(v1.y, w1, fmaf(v1.z, w2, fmaf(v1.w, w3, a1))));
            }
            B[r0 * 256 + o] = fmaxf(a0, 0.f);
            B[(r0 + 1) * 256 + o] = fmaxf(a1, 0.f);
        }
        __syncthreads();
        // L1: 256->256 relu, B->B (register staged)
        {
            const float* wp = ws + WS_UW1T + o;
            float a0 = ub1[o], a1 = a0;
            for (int k4 = 0; k4 < 64; ++k4) {
                float w0 = wp[(4 * k4 + 0) * 256], w1 = wp[(4 * k4 + 1) * 256];
                float w2 = wp[(4 * k4 + 2) * 256], w3 = wp[(4 * k4 + 3) * 256];
                const float4 v0 = *(const float4*)&B[r0 * 256 + 4 * k4];
                const float4 v1 = *(const float4*)&B[(r0 + 1) * 256 + 4 * k4];
                a0 = fmaf(v0.x, w0, fmaf(v0.y, w1, fmaf(v0.z, w2, fmaf(v0.w, w3, a0))));
                a1 = fmaf(v1.x, w0, fmaf(v1.y, w1, fmaf(v1.z, w2, fmaf(v1.w, w3, a1))));
            }
            __syncthreads();
            B[r0 * 256 + o] = fmaxf(a0, 0.f);
            B[(r0 + 1) * 256 + o] = fmaxf(a1, 0.f);
        }
        __syncthreads();
        // L2: 256->16, /N (threads 0..63); agent-store u + 9 Sbuf slots
        if (tid < 64) {
            int r = tid >> 4, oo = tid & 15;
            const float* w2t = ws + WS_UW2T;
            float acc = ub2[oo];
            for (int k4 = 0; k4 < 64; ++k4) {
                const float4 av = *(const float4*)&B[r * 256 + 4 * k4];
                acc = fmaf(av.x, w2t[(4 * k4 + 0) * 16 + oo],
                      fmaf(av.y, w2t[(4 * k4 + 1) * 16 + oo],
                      fmaf(av.z, w2t[(4 * k4 + 2) * 16 + oo],
                      fmaf(av.w, w2t[(4 * k4 + 3) * 16 + oo], acc))));
            }
            float val = acc * (1.f / N_NODES);
            int idx = (n0 + r) * 16 + oo;
            AGST(&u_out[idx], val);
            #pragma unroll
            for (int t = 0; t < NITERS + 1; ++t) AGST(&Sbuf[t * 32000 + idx], val);
        }
        // cab: 128->256 (no bias/relu), A-> cab (agent stores, read cross-block)
        {
            const float* wp = ws + WS_UWCAT + o;
            float a0 = 0.f, a1 = 0.f;
            for (int k4 = 0; k4 < 32; ++k4) {
                float w0 = wp[(4 * k4 + 0) * 256], w1 = wp[(4 * k4 + 1) * 256];
                float w2 = wp[(4 * k4 + 2) * 256], w3 = wp[(4 * k4 + 3) * 256];
                const float4 v0 = *(const float4*)&A[r0 * 128 + 4 * k4];
                const float4 v1 = *(const float4*)&A[(r0 + 1) * 128 + 4 * k4];
                a0 = fmaf(v0.x, w0, fmaf(v0.y, w1, fmaf(v0.z, w2, fmaf(v0.w, w3, a0))));
                a1 = fmaf(v1.x, w0, fmaf(v1.y, w1, fmaf(v1.z, w2, fmaf(v1.w, w3, a1))));
            }
            AGST(&cab[(n0 + r0) * 256 + o], a0);
            AGST(&cab[(n0 + r0 + 1) * 256 + o], a1);
        }
        // resolve -> block-local wflag
        if (tid < 32) {
            int e = e0 + tid;
            wfl_l[tid] = (owner[fi[2 * tid] * N_NODES + se[2 * tid]] == e) ? 1 : 0;
        }
    }
    grid_bar(flags, 2);                  // cab, u, Sbuf final everywhere

    // ================= P_pmlp: f16-split MFMA, 32 edges/block ===============
    // L0 (collapsed): relu(ca[fi] + cb[se] + b0)
    {
        const int cl = tid & 127;
        const int rh = tid >> 7;
        const float bb = b0[cl];
        #pragma unroll 4
        for (int r = rh * 16; r < rh * 16 + 16; ++r) {
            float v = cab[fi[r] * 256 + cl] + cab[se[r] * 256 + 128 + cl] + bb;
            v = fmaxf(v, 0.f);
            _Float16 hv = (_Float16)v;
            Ah[r][cl] = hv;
            Al[r][cl] = (_Float16)(v - (float)hv);
        }
    }
    __syncthreads();

    f32x4 acc[4][2];

    // ---- L1: [64x128] @ W1 -> [64x256] relu ----
    #pragma unroll
    for (int mt = 0; mt < 4; ++mt)
        #pragma unroll
        for (int nt = 0; nt < 2; ++nt) acc[mt][nt] = (f32x4){0.f, 0.f, 0.f, 0.f};
    #pragma unroll
    for (int ks = 0; ks < 4; ++ks) {
        half8 ah[4], al[4];
        #pragma unroll
        for (int mt = 0; mt < 4; ++mt) {
            ah[mt] = *(const half8*)&Ah[16 * mt + lrow][32 * ks + koff];
            al[mt] = *(const half8*)&Al[16 * mt + lrow][32 * ks + koff];
        }
        #pragma unroll
        for (int nt = 0; nt < 2; ++nt) {
            const int n = 32 * wid + 16 * nt + lrow;
            half8 bh = *(const half8*)(fw + F16_W1H + n * 128 + 32 * ks + koff);
            half8 bl = *(const half8*)(fw + F16_W1L + n * 128 + 32 * ks + koff);
            #pragma unroll
            for (int mt = 0; mt < 4; ++mt) {
                acc[mt][nt] = __builtin_amdgcn_mfma_f32_16x16x32_f16(ah[mt], bh, acc[mt][nt], 0, 0, 0);
                acc[mt][nt] = __builtin_amdgcn_mfma_f32_16x16x32_f16(ah[mt], bl, acc[mt][nt], 0, 0, 0);
                acc[mt][nt] = __builtin_amdgcn_mfma_f32_16x16x32_f16(al[mt], bh, acc[mt][nt], 0, 0, 0);
            }
        }
    }
    __syncthreads();
    #pragma unroll
    for (int nt = 0; nt < 2; ++nt) {
        const int col = 32 * wid + 16 * nt + lrow;
        const float bv = b1[col];
        #pragma unroll
        for (int mt = 0; mt < 4; ++mt) {
            #pragma unroll
            for (int r = 0; r < 4; ++r) {
                const int row = 16 * mt + 4 * lgrp + r;   // C: row=(lane>>4)*4+reg
                float v = fmaxf(acc[mt][nt][r] + bv, 0.f);
                _Float16 hv = (_Float16)v;
                Ah[row][col] = hv;
                Al[row][col] = (_Float16)(v - (float)hv);
            }
        }
    }
    __syncthreads();

    // ---- L2: [64x256] @ W2 -> [64x256] relu ----
    #pragma unroll
    for (int mt = 0; mt < 4; ++mt)
        #pragma unroll
        for (int nt = 0; nt < 2; ++nt) acc[mt][nt] = (f32x4){0.f, 0.f, 0.f, 0.f};
    for (int ks = 0; ks < 8; ++ks) {
        half8 ah[4], al[4];
        #pragma unroll
        for (int mt = 0; mt < 4; ++mt) {
            ah[mt] = *(const half8*)&Ah[16 * mt + lrow][32 * ks + koff];
            al[mt] = *(const half8*)&Al[16 * mt + lrow][32 * ks + koff];
        }
        #pragma unroll
        for (int nt = 0; nt < 2; ++nt) {
            const int n = 32 * wid + 16 * nt + lrow;
            half8 bh = *(const half8*)(fw + F16_W2H + n * 256 + 32 * ks + koff);
            half8 bl = *(const half8*)(fw + F16_W2L + n * 256 + 32 * ks + koff);
            #pragma unroll
            for (int mt = 0; mt < 4; ++mt) {
                acc[mt][nt] = __builtin_amdgcn_mfma_f32_16x16x32_f16(ah[mt], bh, acc[mt][nt], 0, 0, 0);
                acc[mt][nt] = __builtin_amdgcn_mfma_f32_16x16x32_f16(ah[mt], bl, acc[mt][nt], 0, 0, 0);
                acc[mt][nt] = __builtin_amdgcn_mfma_f32_16x16x32_f16(al[mt], bh, acc[mt][nt], 0, 0, 0);
            }
        }
    }
    __syncthreads();
    #pragma unroll
    for (int nt = 0; nt < 2; ++nt) {
        const int col = 32 * wid + 16 * nt + lrow;
        const float bv = b2[col];
        #pragma unroll
        for (int mt = 0; mt < 4; ++mt) {
            #pragma unroll
            for (int r = 0; r < 4; ++r) {
                const int row = 16 * mt + 4 * lgrp + r;
                float v = fmaxf(acc[mt][nt][r] + bv, 0.f);
                _Float16 hv = (_Float16)v;
                Ah[row][col] = hv;
                Al[row][col] = (_Float16)(v - (float)hv);
            }
        }
    }
    __syncthreads();

    // ---- L3: [64x256] @ W3 -> [64x16] relu (waves 0..3, full K) ----
    if (wid < 4) {
        f32x4 acc3 = {0.f, 0.f, 0.f, 0.f};
        #pragma unroll
        for (int ks = 0; ks < 8; ++ks) {
            half8 ah = *(const half8*)&Ah[16 * wid + lrow][32 * ks + koff];
            half8 al = *(const half8*)&Al[16 * wid + lrow][32 * ks + koff];
            half8 bh = *(const half8*)(fw + F16_W3H + lrow * 256 + 32 * ks + koff);
            half8 bl = *(const half8*)(fw + F16_W3L + lrow * 256 + 32 * ks + koff);
            acc3 = __builtin_amdgcn_mfma_f32_16x16x32_f16(ah, bh, acc3, 0, 0, 0);
            acc3 = __builtin_amdgcn_mfma_f32_16x16x32_f16(ah, bl, acc3, 0, 0, 0);
            acc3 = __builtin_amdgcn_mfma_f32_16x16x32_f16(al, bh, acc3, 0, 0, 0);
        }
        const float b3v = b3[lrow];
        #pragma unroll
        for (int r = 0; r < 4; ++r)
            C16[16 * wid + 4 * lgrp + r][lrow] = fmaxf(acc3[r] + b3v, 0.f);
    }
    __syncthreads();   // Ah/Al dead: pTl overlays Ah

    float* pTl = (float*)Ah;   // [32][256] floats = 32 KB

    // ---- L4: [64x16] @ W4 -> [64x256]; p_out agent-store; pT -> LDS ----
    {
        half8 a4h[4], a4l[4];
        #pragma unroll
        for (int mt = 0; mt < 4; ++mt) {
            half8 hh, ll;
            #pragma unroll
            for (int j = 0; j < 8; ++j) { hh[j] = (_Float16)0.f; ll[j] = (_Float16)0.f; }
            if (lgrp < 2) {
                #pragma unroll
                for (int j = 0; j < 8; ++j) {
                    float v = C16[16 * mt + lrow][8 * lgrp + j];
                    _Float16 hv = (_Float16)v;
                    hh[j] = hv;
                    ll[j] = (_Float16)(v - (float)hv);
                }
            }
            a4h[mt] = hh; a4l[mt] = ll;
        }
        #pragma unroll
        for (int nt = 0; nt < 2; ++nt) {
            const int o = 32 * wid + 16 * nt + lrow;
            const float b4v = b4[o];
            half8 bh = *(const half8*)(fw + F16_W4H + o * 32 + koff);
            half8 bl = *(const half8*)(fw + F16_W4L + o * 32 + koff);
            const int ot = (o & 15) * 16 + (o >> 4);   // pT[e][aj][ai]
            #pragma unroll
            for (int mt = 0; mt < 4; ++mt) {
                f32x4 a4 = {0.f, 0.f, 0.f, 0.f};
                a4 = __builtin_amdgcn_mfma_f32_16x16x32_f16(a4h[mt], bh, a4, 0, 0, 0);
                a4 = __builtin_amdgcn_mfma_f32_16x16x32_f16(a4h[mt], bl, a4, 0, 0, 0);
                a4 = __builtin_amdgcn_mfma_f32_16x16x32_f16(a4l[mt], bh, a4, 0, 0, 0);
                const int s0 = 8 * mt + 2 * lgrp;
                float pav = (0.5f * (a4[0] + a4[1]) + b4v) * (1.f / NE);
                float pbv = (0.5f * (a4[2] + a4[3]) + b4v) * (1.f / NE);
                AGST(&p_out[(e0 + s0) * 256 + o], pav);
                AGST(&p_out[(e0 + s0 + 1) * 256 + o], pbv);
                pTl[s0 * 256 + ot] = pav;
                pTl[(s0 + 1) * 256 + ot] = pbv;
            }
        }
    }
    __syncthreads();

    // ================= MP phase =================
    const int g = tid >> 4;
    const int L = tid & 15;
    const int gi2 = fi[2 * g], gj2 = se[2 * g];
    const int wf = wfl_l[g];
    float pv[16];
    #pragma unroll
    for (int a4i = 0; a4i < 4; ++a4i) {
        float4 v = *(const float4*)&pTl[g * 256 + L * 16 + 4 * a4i];
        pv[4 * a4i + 0] = v.x; pv[4 * a4i + 1] = v.y;
        pv[4 * a4i + 2] = v.z; pv[4 * a4i + 3] = v.w;
    }
    float vmax = -INFINITY;
    #pragma unroll
    for (int a = 0; a < 16; ++a) vmax = fmaxf(vmax, pv[a]);
    float mold_ij = 0.f, mold_ji = 0.f;

    for (int t = 0; t < NITERS; ++t) {
        const float* uSo = Sbuf + t * 32000;
        float* uSn = Sbuf + (t + 1) * 32000;
        const float bi = uSo[gi2 * 16 + L] - mold_ij;
        const float bj = uSo[gj2 * 16 + L] - mold_ji;
        float mj = -INFINITY;
        #pragma unroll
        for (int a = 0; a < 16; ++a)
            mj = fmaxf(mj, pv[a] + __shfl(bi, a, 16));
        float mi = vmax + bj;
        float sj = mj, si = mi;
        #pragma unroll
        for (int off = 1; off < 16; off <<= 1) {
            sj += __shfl_xor(sj, off, 16);
            si += __shfl_xor(si, off, 16);
        }
        mj -= sj * (1.f / 16.f);
        mi -= si * (1.f / 16.f);
        mold_ji = mj;
        mold_ij = mi;
        if (wf) {
            atomicAdd(&uSn[gj2 * 16 + L], mj);
            atomicAdd(&uSn[gi2 * 16 + L], mi);
        }
        grid_bar(flags, 3 + t);              // Sbuf[t+1] complete
    }

    // ---- node-all: blocks 0..287, one t per 36-block group ----
    if (bid < 288) {
        const int t2 = bid / 36;
        const int r2 = (bid % 36) * 512 + tid;
        const float* Sn = Sbuf + (t2 + 1) * 32000;
        float partial = 0.f;
        if (r2 < N_NODES) {
            int n = r2;
            float bv = Sn[n * 16];
            int best = 0;
            #pragma unroll
            for (int a = 1; a < 16; ++a) {
                float v = Sn[n * 16 + a];
                if (v > bv) { bv = v; best = a; }
            }
            AGST(&aidx[t2 * N_NODES + n], best);
            partial = u_out[n * 16 + best];
        } else if (r2 < N_NODES + NE) {
            int ee = r2 - N_NODES;
            int ii = edges[2 * ee], jj = edges[2 * ee + 1];
            float bvi = Sn[ii * 16]; int ai = 0;
            #pragma unroll
            for (int a = 1; a < 16; ++a) {
                float v = Sn[ii * 16 + a];
                if (v > bvi) { bvi = v; ai = a; }
            }
            float bvj = Sn[jj * 16]; int aj = 0;
            #pragma unroll
            for (int a = 1; a < 16; ++a) {
                float v = Sn[jj * 16 + a];
                if (v > bvj) { bvj = v; aj = a; }
            }
            partial = p_out[ee * 256 + ai * 16 + aj];
        }
        #pragma unroll
        for (int off = 1; off < 64; off <<= 1)
            partial += __shfl_xor(partial, off, 64);
        if ((tid & 63) == 0) atomicAdd(&q[t2], partial);
    }
    grid_bar(flags, NITERS + 3);             // all q[t], aidx final

    // ---- final: running strict-> max over iters, one-hot a ----
    const int r = bid * 512 + tid;
    if (r < N_NODES * 16) {
        float cur = 0.f; int best_t = -1;
        #pragma unroll
        for (int t2 = 0; t2 < NITERS; ++t2) {
            float qv = q[t2];
            if (qv > cur) { cur = qv; best_t = t2; }
        }
        int n = r >> 4, c = r & 15;
        float val = 0.f;
        if (best_t >= 0 && aidx[best_t * N_NODES + n] == c) val = 1.f;
        a_out[r] = val;
        if (r == 0) q_out[0] = cur;
    }
}

extern "C" void kernel_launch(void* const* d_in, const int* in_sizes, int n_in,
                              void* d_out, int out_size, void* d_ws, size_t ws_size,
                              hipStream_t stream)
{
    (void)in_sizes; (void)n_in; (void)out_size; (void)ws_size;
    const float* x    = (const float*)d_in[0];
    const float* pa   = (const float*)d_in[1];
    const float* st   = (const float*)d_in[2];
    const int*   edges= (const int*)d_in[3];
    const float* gwih = (const float*)d_in[4];
    const float* gwhh = (const float*)d_in[5];
    const float* gbih = (const float*)d_in[6];
    const float* gbhh = (const float*)d_in[7];
    const float* uW0 = (const float*)d_in[8];  const float* ub0 = (const float*)d_in[9];
    const float* uW1 = (const float*)d_in[10]; const float* ub1 = (const float*)d_in[11];
    const float* uW2 = (const float*)d_in[12]; const float* ub2 = (const float*)d_in[13];
    const float* pW0 = (const float*)d_in[14]; const float* pb0 = (const float*)d_in[15];
    const float* pW1 = (const float*)d_in[16]; const float* pb1 = (const float*)d_in[17];
    const float* pW2 = (const float*)d_in[18]; const float* pb2 = (const float*)d_in[19];
    const float* pW3 = (const float*)d_in[20]; const float* pb3 = (const float*)d_in[21];
    const float* pW4 = (const float*)d_in[22]; const float* pb4 = (const float*)d_in[23];

    float* out   = (float*)d_out;
    float* a_out = out;                 // 32000
    float* q_out = out + 32000;         // 1
    float* u_out = out + 32001;         // 32000
    float* p_out = out + 64001;         // 4,096,000
    float* h_out = out + 4160001;       // 256,000 (state_out)

    float* ws = (float*)d_ws;

    setup_kernel<<<1087, 256, 0, stream>>>(ws, edges, uW0, uW1, uW2,
                                           pW0, pW1, pW2, pW3, pW4, gwih, gwhh);
    mega_kernel<<<NBLK, 512, 0, stream>>>(x, pa, st, gbih, gbhh,
                                          ub0, ub1, ub2,
                                          pb0, pb1, pb2, pb3, pb4,
                                          edges, ws, h_out, u_out, p_out,
                                          a_out, q_out);
}

// Round 11
// 248.746 us; speedup vs baseline: 1.1513x; 1.0514x over previous
//
#include <hip/hip_runtime.h>
#include <math.h>

#define N_NODES 2000
#define NA 16
#define NOBS 64
#define NH 128
#define NE 16000
#define NITERS 8

// ---------------- workspace layout (float offsets) ----------------
#define WS_MSG       0                       // f16-split p weights
#define WS_FLAGS     300000                  // barrier flags: 500*32 + 8*32 ints (zeroed each run)
#define WS_Q         512000                  // q[8] (+pad, zeroed each run)
#define WS_SBUF      512016                  // 9 x 32000 uS buffers (agent-stored by P_u)
#define WS_AIDX      800016                  // int[8*2000]
#define WS_W         816016                  // (unused; wflag is block-local LDS)
#define WS_PT        832016                  // owner map (4,000,000 ints)
#define WS_GIT       (WS_PT + 4000000)       // gru wihT k-panel 80x384 = 30720
#define WS_GHT       (WS_GIT + 30720)        // gru whhT k-panel 128x384 = 49152
#define WS_WB        4928016                 // transposed fp32 weights (umlp)
#define WS_UW0T      (WS_WB + 0)             // 128x256
#define WS_UWCAT     (WS_WB + 32768)         // 128x256  [W0a@h | W0b@h] combined
#define WS_UW1T      (WS_WB + 65536)         // 256x256
#define WS_UW2T      (WS_WB + 131072)        // 256x16
#define WS_CAB       (WS_WB + 241664)        // cab[2000][256] = 512000

// f16 weight offsets (in _Float16 units) within WS_MSG region:
#define F16_W1H 0        // [256][128]
#define F16_W1L 32768
#define F16_W2H 65536    // [256][256]
#define F16_W2L 131072
#define F16_W3H 196608   // [16][256]
#define F16_W3L 200704
#define F16_W4H 204800   // [256][32] (k padded 16->32 with zeros)
#define F16_W4L 212992

#define NBLK 500         // mega grid; gen8 lines start at flags + NBLK*32

typedef _Float16 half8 __attribute__((ext_vector_type(8)));
typedef float f32x4 __attribute__((ext_vector_type(4)));

#define AGST(p, v) __hip_atomic_store((p), (v), __ATOMIC_RELAXED, __HIP_MEMORY_SCOPE_AGENT)

// ---------------- setup: coalesced-read / scattered-write transposes ---------
// Blocks 0..1335 (single pass, 341904 tasks); blocks 1336..1398 owner-init.
// Every weight element is READ at consecutive addresses (linear stream); the
// transpose scatter is on the STORE side (fire-and-forget, no latency stall).
__global__ __launch_bounds__(256) void setup_kernel(
    float* __restrict__ ws, const int* __restrict__ edges,
    const float* __restrict__ uW0, const float* __restrict__ uW1,
    const float* __restrict__ uW2, const float* __restrict__ pW0,
    const float* __restrict__ pW1, const float* __restrict__ pW2,
    const float* __restrict__ pW3, const float* __restrict__ pW4,
    const float* __restrict__ gwih, const float* __restrict__ gwhh)
{
    if (blockIdx.x >= 1336) {
        int e = (blockIdx.x - 1336) * 256 + threadIdx.x;
        if (e < NE) {
            int i = edges[2 * e], j = edges[2 * e + 1];
            ((int*)(ws + WS_PT))[i * N_NODES + j] = -1;
        }
        return;
    }
    int t = blockIdx.x * 256 + threadIdx.x;
    if (t >= 341904) return;
    if (t < 16) { ws[WS_Q + t] = 0.f; return; }
    t -= 16;
    if (t < 16256) { ((int*)(ws + WS_FLAGS))[t] = 0; return; }
    t -= 16256;
    if (t < 32768) {                       // uW0 [256][128] -> uW0T [128][256]
        int o = t >> 7, k = t & 127;
        ws[WS_UW0T + k * 256 + o] = uW0[t];
        return;
    }
    t -= 32768;
    if (t < 32768) {                       // pW0 [128][256] -> UWCAT [128][256]
        int r = t >> 8, c = t & 255;
        float v = pW0[t];
        int dst = (c < 128) ? (c * 256 + r) : ((c - 128) * 256 + r + 128);
        ws[WS_UWCAT + dst] = v;
        return;
    }
    t -= 32768;
    if (t < 65536) {                       // uW1 [256][256] -> uW1T
        int r = t >> 8, c = t & 255;
        ws[WS_UW1T + c * 256 + r] = uW1[t];
        return;
    }
    t -= 65536;
    if (t < 4096) {                        // uW2 [16][256] -> uW2T [256][16]
        int r = t >> 8, c = t & 255;
        ws[WS_UW2T + c * 16 + r] = uW2[t];
        return;
    }
    t -= 4096;
    if (t < 30720) {                       // gwih [384][80] -> k4-panel
        int g = t / 80, kk = t % 80;
        ws[WS_GIT + (kk >> 2) * 1536 + g * 4 + (kk & 3)] = gwih[t];
        return;
    }
    t -= 30720;
    if (t < 49152) {                       // gwhh [384][128] -> k4-panel
        int g = t >> 7, kk = t & 127;
        ws[WS_GHT + (kk >> 2) * 1536 + g * 4 + (kk & 3)] = gwhh[t];
        return;
    }
    t -= 49152;
    {                                      // f16 hi/lo split (reads coalesced)
        int q = t;                         // 0..110591
        _Float16* fwp = (_Float16*)ws;     // WS_MSG = 0
        float v; int hoff, loff;
        if (q < 32768) {                   // pW1: [256][128]
            v = pW1[q]; hoff = F16_W1H + q; loff = F16_W1L + q;
        } else if (q < 98304) {            // pW2: [256][256]
            int z = q - 32768; v = pW2[z];
            hoff = F16_W2H + z; loff = F16_W2L + z;
        } else if (q < 102400) {           // pW3: [16][256]
            int z = q - 98304; v = pW3[z];
            hoff = F16_W3H + z; loff = F16_W3L + z;
        } else {                           // pW4: [256][16] -> [256][32] padded
            int z = q - 102400; int n = z >> 5, kk = z & 31;
            v = (kk < 16) ? pW4[n * 16 + kk] : 0.f;
            hoff = F16_W4H + z; loff = F16_W4L + z;
        }
        _Float16 hv = (_Float16)v;
        fwp[hoff] = hv;
        fwp[loff] = (_Float16)(v - (float)hv);
    }
}

// ---------------- contention-free software grid barrier (512 thr) ------------
__device__ __forceinline__ void grid_bar(int* flags, int gval)
{
    int* gen8 = flags + NBLK * 32;
    __syncthreads();   // compiler drains vmcnt before s_barrier: all this
                       // block's stores/atomics complete before arrival
    if (blockIdx.x == 0) {
        const int i = threadIdx.x;
        if (i >= 1 && i < NBLK) {
            while (__hip_atomic_load(&flags[i * 32], __ATOMIC_RELAXED,
                                     __HIP_MEMORY_SCOPE_AGENT) < gval)
                __builtin_amdgcn_s_sleep(2);
        }
        __syncthreads();
        if (i < 8)
            __hip_atomic_store(&gen8[i * 32], gval, __ATOMIC_RELAXED,
                               __HIP_MEMORY_SCOPE_AGENT);
    } else {
        if (threadIdx.x == 0) {
            asm volatile("s_waitcnt vmcnt(0)" ::: "memory");
            __hip_atomic_store(&flags[blockIdx.x * 32], gval, __ATOMIC_RELAXED,
                               __HIP_MEMORY_SCOPE_AGENT);
            while (__hip_atomic_load(&gen8[(blockIdx.x & 7) * 32],
                                     __ATOMIC_RELAXED,
                                     __HIP_MEMORY_SCOPE_AGENT) < gval)
                __builtin_amdgcn_s_sleep(2);
        }
        __syncthreads();
    }
}

// ---------------- mega: gru -> u/cab/resolve -> pmlp -> MP (one kernel) ------
__global__ __launch_bounds__(512, 4) void mega_kernel(
    const float* __restrict__ x, const float* __restrict__ pa,
    const float* __restrict__ st, const float* __restrict__ bih,
    const float* __restrict__ bhh, const float* __restrict__ ub0,
    const float* __restrict__ ub1, const float* __restrict__ ub2,
    const float* __restrict__ b0, const float* __restrict__ b1,
    const float* __restrict__ b2, const float* __restrict__ b3,
    const float* __restrict__ b4, const int* __restrict__ edges,
    float* __restrict__ ws, float* __restrict__ h_out,
    float* __restrict__ u_out, float* __restrict__ p_out,
    float* __restrict__ a_out, float* __restrict__ q_out)
{
    __shared__ __align__(16) _Float16 Ah[64][264];
    __shared__ __align__(16) _Float16 Al[64][264];
    __shared__ float C16[64][16];
    __shared__ int fi[64], se[64];
    __shared__ int wfl_l[32];

    const int tid  = threadIdx.x;
    const int bid  = blockIdx.x;
    const int e0   = bid * 32;
    const int wid  = tid >> 6;        // wave 0..7
    const int lane = tid & 63;
    const int lrow = lane & 15;
    const int lgrp = lane >> 4;
    const int koff = 8 * lgrp;

    float* sm = (float*)&Ah[0][0];    // scratch union inside Ah (8448 floats)
    int*   flags = (int*)(ws + WS_FLAGS);
    int*   owner = (int*)(ws + WS_PT);
    const _Float16* fw = (const _Float16*)ws;
    float* Sbuf = ws + WS_SBUF;
    float* q    = ws + WS_Q;
    int*   aidx = (int*)(ws + WS_AIDX);
    float* cab  = ws + WS_CAB;

    if (tid < 32) {
        int i = edges[2 * (e0 + tid)], j = edges[2 * (e0 + tid) + 1];
        fi[2 * tid] = i;     se[2 * tid] = j;
        fi[2 * tid + 1] = j; se[2 * tid + 1] = i;
    }

    // ================= P_gru: 4 nodes/block + claim =================
    // One gate per thread (384 threads), all 4 rows: weight column read ONCE
    // per block (320 KB vs 1.25 MB), coalesced float4 weight loads, enc/hp
    // LDS broadcasts, 8 independent FMA chains.
    {
        float* enc = sm;              // [4][80]
        float* hp  = sm + 320;        // [4][128]
        float* gi  = sm + 832;        // [4][384]
        float* gh  = sm + 2368;       // [4][384]
        float* A   = sm + 3904;       // [4][128] persists into P_u
        const float* wihT = ws + WS_GIT;
        const float* whhT = ws + WS_GHT;
        const int n0 = bid * 4;

        if (tid < 320) {
            int r = tid / 80, c = tid % 80;
            enc[r * 80 + c] = (c < 64) ? x[(n0 + r) * 64 + c]
                                       : pa[(n0 + r) * 16 + (c - 64)];
        }
        {
            int r = tid >> 7, c = tid & 127;
            hp[r * 128 + c] = st[(n0 + r) * 128 + c];
        }
        __syncthreads();

        if (tid < 384) {
            const int g = tid;
            float s1[4], s2[4];
            const float bi_ = bih[g], bh_ = bhh[g];
            #pragma unroll
            for (int r = 0; r < 4; ++r) { s1[r] = bi_; s2[r] = bh_; }
            #pragma unroll 5
            for (int k4 = 0; k4 < 20; ++k4) {
                const float4 wv = *(const float4*)&wihT[k4 * 1536 + g * 4];
                #pragma unroll
                for (int r = 0; r < 4; ++r) {
                    const float4 ev = *(const float4*)&enc[r * 80 + 4 * k4];
                    s1[r] = fmaf(ev.x, wv.x, fmaf(ev.y, wv.y, fmaf(ev.z, wv.z, fmaf(ev.w, wv.w, s1[r]))));
                }
            }
            #pragma unroll 4
            for (int k4 = 0; k4 < 32; ++k4) {
                const float4 wv = *(const float4*)&whhT[k4 * 1536 + g * 4];
                #pragma unroll
                for (int r = 0; r < 4; ++r) {
                    const float4 hv = *(const float4*)&hp[r * 128 + 4 * k4];
                    s2[r] = fmaf(hv.x, wv.x, fmaf(hv.y, wv.y, fmaf(hv.z, wv.z, fmaf(hv.w, wv.w, s2[r]))));
                }
            }
            #pragma unroll
            for (int r = 0; r < 4; ++r) {
                gi[r * 384 + g] = s1[r];
                gh[r * 384 + g] = s2[r];
            }
        }
        __syncthreads();

        {
            int r = tid >> 7, c = tid & 127;
            float rr = 1.f / (1.f + expf(-(gi[r * 384 + c] + gh[r * 384 + c])));
            float zz = 1.f / (1.f + expf(-(gi[r * 384 + 128 + c] + gh[r * 384 + 128 + c])));
            float nn = tanhf(gi[r * 384 + 256 + c] + rr * gh[r * 384 + 256 + c]);
            float hv = (1.f - zz) * nn + zz * hp[r * 128 + c];
            A[r * 128 + c] = hv;                  // block-local handoff
            h_out[(n0 + r) * 128 + c] = hv;       // state_out output
        }
        if (tid < 32) {
            int e = e0 + tid;
            atomicMax(&owner[fi[2 * tid] * N_NODES + se[2 * tid]], e);
        }
    }
    grid_bar(flags, 1);                  // owner final (h is block-local)

    // ================= P_u: u-MLP + cab + resolve (4 nodes/block) ===========
    {
        float* A = sm + 3904;            // h rows (from P_gru, same block)
        float* B = sm + 4416;            // [4][256]
        const int n0 = bid * 4;
        const int o  = tid & 255;
        const int r0 = (tid >> 8) * 2;   // rows r0, r0+1

        // L0: 128->256 relu, A->B
        {
            const float* wp = ws + WS_UW0T + o;
            float a0 = ub0[o], a1 = a0;
            for (int k4 = 0; k4 < 32; ++k4) {
                float w0 = wp[(4 * k4 + 0) * 256], w1 = wp[(4 * k4 + 1) * 256];
                float w2 = wp[(4 * k4 + 2) * 256], w3 = wp[(4 * k4 + 3) * 256];
                const float4 v0 = *(const float4*)&A[r0 * 128 + 4 * k4];
                const float4 v1 = *(const float4*)&A[(r0 + 1) * 128 + 4 * k4];
                a0 = fmaf(v0.x, w0, fmaf(v0.y, w1, fmaf(v0.z, w2, fmaf(v0.w, w3, a0))));
                a1 = fmaf(v1.x, w0, fmaf(v1.y, w1, fmaf(v1.z, w2, fmaf(v1.w, w3, a1))));
            }
            B[r0 * 256 + o] = fmaxf(a0, 0.f);
            B[(r0 + 1) * 256 + o] = fmaxf(a1, 0.f);
        }
        __syncthreads();
        // L1: 256->256 relu, B->B (register staged)
        {
            const float* wp = ws + WS_UW1T + o;
            float a0 = ub1[o], a1 = a0;
            for (int k4 = 0; k4 < 64; ++k4) {
                float w0 = wp[(4 * k4 + 0) * 256], w1 = wp[(4 * k4 + 1) * 256];
                float w2 = wp[(4 * k4 + 2) * 256], w3 = wp[(4 * k4 + 3) * 256];
                const float4 v0 = *(const float4*)&B[r0 * 256 + 4 * k4];
                const float4 v1 = *(const float4*)&B[(r0 + 1) * 256 + 4 * k4];
                a0 = fmaf(v0.x, w0, fmaf(v0.y, w1, fmaf(v0.z, w2, fmaf(v0.w, w3, a0))));
                a1 = fmaf(v1.x, w0, fmaf(v1.y, w1, fmaf(v1.z, w2, fmaf(v1.w, w3, a1))));
            }
            __syncthreads();
            B[r0 * 256 + o] = fmaxf(a0, 0.f);
            B[(r0 + 1) * 256 + o] = fmaxf(a1, 0.f);
        }
        __syncthreads();
        // L2: 256->16, /N (threads 0..63); agent-store u + 9 Sbuf slots
        if (tid < 64) {
            int r = tid >> 4, oo = tid & 15;
            const float* w2t = ws + WS_UW2T;
            float acc = ub2[oo];
            for (int k4 = 0; k4 < 64; ++k4) {
                const float4 av = *(const float4*)&B[r * 256 + 4 * k4];
                acc = fmaf(av.x, w2t[(4 * k4 + 0) * 16 + oo],
                      fmaf(av.y, w2t[(4 * k4 + 1) * 16 + oo],
                      fmaf(av.z, w2t[(4 * k4 + 2) * 16 + oo],
                      fmaf(av.w, w2t[(4 * k4 + 3) * 16 + oo], acc))));
            }
            float val = acc * (1.f / N_NODES);
            int idx = (n0 + r) * 16 + oo;
            AGST(&u_out[idx], val);
            #pragma unroll
            for (int t = 0; t < NITERS + 1; ++t) AGST(&Sbuf[t * 32000 + idx], val);
        }
        // cab: 128->256 (no bias/relu), A-> cab (agent stores, read cross-block)
        {
            const float* wp = ws + WS_UWCAT + o;
            float a0 = 0.f, a1 = 0.f;
            for (int k4 = 0; k4 < 32; ++k4) {
                float w0 = wp[(4 * k4 + 0) * 256], w1 = wp[(4 * k4 + 1) * 256];
                float w2 = wp[(4 * k4 + 2) * 256], w3 = wp[(4 * k4 + 3) * 256];
                const float4 v0 = *(const float4*)&A[r0 * 128 + 4 * k4];
                const float4 v1 = *(const float4*)&A[(r0 + 1) * 128 + 4 * k4];
                a0 = fmaf(v0.x, w0, fmaf(v0.y, w1, fmaf(v0.z, w2, fmaf(v0.w, w3, a0))));
                a1 = fmaf(v1.x, w0, fmaf(v1.y, w1, fmaf(v1.z, w2, fmaf(v1.w, w3, a1))));
            }
            AGST(&cab[(n0 + r0) * 256 + o], a0);
            AGST(&cab[(n0 + r0 + 1) * 256 + o], a1);
        }
        // resolve -> block-local wflag
        if (tid < 32) {
            int e = e0 + tid;
            wfl_l[tid] = (owner[fi[2 * tid] * N_NODES + se[2 * tid]] == e) ? 1 : 0;
        }
    }
    grid_bar(flags, 2);                  // cab, u, Sbuf final everywhere

    // ================= P_pmlp: f16-split MFMA, 32 edges/block ===============
    // L0 (collapsed): relu(ca[fi] + cb[se] + b0)
    {
        const int cl = tid & 127;
        const int rh = tid >> 7;
        const float bb = b0[cl];
        #pragma unroll 4
        for (int r = rh * 16; r < rh * 16 + 16; ++r) {
            float v = cab[fi[r] * 256 + cl] + cab[se[r] * 256 + 128 + cl] + bb;
            v = fmaxf(v, 0.f);
            _Float16 hv = (_Float16)v;
            Ah[r][cl] = hv;
            Al[r][cl] = (_Float16)(v - (float)hv);
        }
    }
    __syncthreads();

    f32x4 acc[4][2];

    // ---- L1: [64x128] @ W1 -> [64x256] relu ----
    #pragma unroll
    for (int mt = 0; mt < 4; ++mt)
        #pragma unroll
        for (int nt = 0; nt < 2; ++nt) acc[mt][nt] = (f32x4){0.f, 0.f, 0.f, 0.f};
    #pragma unroll
    for (int ks = 0; ks < 4; ++ks) {
        half8 ah[4], al[4];
        #pragma unroll
        for (int mt = 0; mt < 4; ++mt) {
            ah[mt] = *(const half8*)&Ah[16 * mt + lrow][32 * ks + koff];
            al[mt] = *(const half8*)&Al[16 * mt + lrow][32 * ks + koff];
        }
        #pragma unroll
        for (int nt = 0; nt < 2; ++nt) {
            const int n = 32 * wid + 16 * nt + lrow;
            half8 bh = *(const half8*)(fw + F16_W1H + n * 128 + 32 * ks + koff);
            half8 bl = *(const half8*)(fw + F16_W1L + n * 128 + 32 * ks + koff);
            #pragma unroll
            for (int mt = 0; mt < 4; ++mt) {
                acc[mt][nt] = __builtin_amdgcn_mfma_f32_16x16x32_f16(ah[mt], bh, acc[mt][nt], 0, 0, 0);
                acc[mt][nt] = __builtin_amdgcn_mfma_f32_16x16x32_f16(ah[mt], bl, acc[mt][nt], 0, 0, 0);
                acc[mt][nt] = __builtin_amdgcn_mfma_f32_16x16x32_f16(al[mt], bh, acc[mt][nt], 0, 0, 0);
            }
        }
    }
    __syncthreads();
    #pragma unroll
    for (int nt = 0; nt < 2; ++nt) {
        const int col = 32 * wid + 16 * nt + lrow;
        const float bv = b1[col];
        #pragma unroll
        for (int mt = 0; mt < 4; ++mt) {
            #pragma unroll
            for (int r = 0; r < 4; ++r) {
                const int row = 16 * mt + 4 * lgrp + r;   // C: row=(lane>>4)*4+reg
                float v = fmaxf(acc[mt][nt][r] + bv, 0.f);
                _Float16 hv = (_Float16)v;
                Ah[row][col] = hv;
                Al[row][col] = (_Float16)(v - (float)hv);
            }
        }
    }
    __syncthreads();

    // ---- L2: [64x256] @ W2 -> [64x256] relu ----
    #pragma unroll
    for (int mt = 0; mt < 4; ++mt)
        #pragma unroll
        for (int nt = 0; nt < 2; ++nt) acc[mt][nt] = (f32x4){0.f, 0.f, 0.f, 0.f};
    for (int ks = 0; ks < 8; ++ks) {
        half8 ah[4], al[4];
        #pragma unroll
        for (int mt = 0; mt < 4; ++mt) {
            ah[mt] = *(const half8*)&Ah[16 * mt + lrow][32 * ks + koff];
            al[mt] = *(const half8*)&Al[16 * mt + lrow][32 * ks + koff];
        }
        #pragma unroll
        for (int nt = 0; nt < 2; ++nt) {
            const int n = 32 * wid + 16 * nt + lrow;
            half8 bh = *(const half8*)(fw + F16_W2H + n * 256 + 32 * ks + koff);
            half8 bl = *(const half8*)(fw + F16_W2L + n * 256 + 32 * ks + koff);
            #pragma unroll
            for (int mt = 0; mt < 4; ++mt) {
                acc[mt][nt] = __builtin_amdgcn_mfma_f32_16x16x32_f16(ah[mt], bh, acc[mt][nt], 0, 0, 0);
                acc[mt][nt] = __builtin_amdgcn_mfma_f32_16x16x32_f16(ah[mt], bl, acc[mt][nt], 0, 0, 0);
                acc[mt][nt] = __builtin_amdgcn_mfma_f32_16x16x32_f16(al[mt], bh, acc[mt][nt], 0, 0, 0);
            }
        }
    }
    __syncthreads();
    #pragma unroll
    for (int nt = 0; nt < 2; ++nt) {
        const int col = 32 * wid + 16 * nt + lrow;
        const float bv = b2[col];
        #pragma unroll
        for (int mt = 0; mt < 4; ++mt) {
            #pragma unroll
            for (int r = 0; r < 4; ++r) {
                const int row = 16 * mt + 4 * lgrp + r;
                float v = fmaxf(acc[mt][nt][r] + bv, 0.f);
                _Float16 hv = (_Float16)v;
                Ah[row][col] = hv;
                Al[row][col] = (_Float16)(v - (float)hv);
            }
        }
    }
    __syncthreads();

    // ---- L3: [64x256] @ W3 -> [64x16] relu (waves 0..3, full K) ----
    if (wid < 4) {
        f32x4 acc3 = {0.f, 0.f, 0.f, 0.f};
        #pragma unroll
        for (int ks = 0; ks < 8; ++ks) {
            half8 ah = *(const half8*)&Ah[16 * wid + lrow][32 * ks + koff];
            half8 al = *(const half8*)&Al[16 * wid + lrow][32 * ks + koff];
            half8 bh = *(const half8*)(fw + F16_W3H + lrow * 256 + 32 * ks + koff);
            half8 bl = *(const half8*)(fw + F16_W3L + lrow * 256 + 32 * ks + koff);
            acc3 = __builtin_amdgcn_mfma_f32_16x16x32_f16(ah, bh, acc3, 0, 0, 0);
            acc3 = __builtin_amdgcn_mfma_f32_16x16x32_f16(ah, bl, acc3, 0, 0, 0);
            acc3 = __builtin_amdgcn_mfma_f32_16x16x32_f16(al, bh, acc3, 0, 0, 0);
        }
        const float b3v = b3[lrow];
        #pragma unroll
        for (int r = 0; r < 4; ++r)
            C16[16 * wid + 4 * lgrp + r][lrow] = fmaxf(acc3[r] + b3v, 0.f);
    }
    __syncthreads();   // Ah/Al dead: pTl overlays Ah

    float* pTl = (float*)Ah;   // [32][256] floats = 32 KB

    // ---- L4: [64x16] @ W4 -> [64x256]; p_out agent-store; pT -> LDS ----
    {
        half8 a4h[4], a4l[4];
        #pragma unroll
        for (int mt = 0; mt < 4; ++mt) {
            half8 hh, ll;
            #pragma unroll
            for (int j = 0; j < 8; ++j) { hh[j] = (_Float16)0.f; ll[j] = (_Float16)0.f; }
            if (lgrp < 2) {
                #pragma unroll
                for (int j = 0; j < 8; ++j) {
                    float v = C16[16 * mt + lrow][8 * lgrp + j];
                    _Float16 hv = (_Float16)v;
                    hh[j] = hv;
                    ll[j] = (_Float16)(v - (float)hv);
                }
            }
            a4h[mt] = hh; a4l[mt] = ll;
        }
        #pragma unroll
        for (int nt = 0; nt < 2; ++nt) {
            const int o = 32 * wid + 16 * nt + lrow;
            const float b4v = b4[o];
            half8 bh = *(const half8*)(fw + F16_W4H + o * 32 + koff);
            half8 bl = *(const half8*)(fw + F16_W4L + o * 32 + koff);
            const int ot = (o & 15) * 16 + (o >> 4);   // pT[e][aj][ai]
            #pragma unroll
            for (int mt = 0; mt < 4; ++mt) {
                f32x4 a4 = {0.f, 0.f, 0.f, 0.f};
                a4 = __builtin_amdgcn_mfma_f32_16x16x32_f16(a4h[mt], bh, a4, 0, 0, 0);
                a4 = __builtin_amdgcn_mfma_f32_16x16x32_f16(a4h[mt], bl, a4, 0, 0, 0);
                a4 = __builtin_amdgcn_mfma_f32_16x16x32_f16(a4l[mt], bh, a4, 0, 0, 0);
                const int s0 = 8 * mt + 2 * lgrp;
                float pav = (0.5f * (a4[0] + a4[1]) + b4v) * (1.f / NE);
                float pbv = (0.5f * (a4[2] + a4[3]) + b4v) * (1.f / NE);
                AGST(&p_out[(e0 + s0) * 256 + o], pav);
                AGST(&p_out[(e0 + s0 + 1) * 256 + o], pbv);
                pTl[s0 * 256 + ot] = pav;
                pTl[(s0 + 1) * 256 + ot] = pbv;
            }
        }
    }
    __syncthreads();

    // ================= MP phase =================
    const int g = tid >> 4;
    const int L = tid & 15;
    const int gi2 = fi[2 * g], gj2 = se[2 * g];
    const int wf = wfl_l[g];
    float pv[16];
    #pragma unroll
    for (int a4i = 0; a4i < 4; ++a4i) {
        float4 v = *(const float4*)&pTl[g * 256 + L * 16 + 4 * a4i];
        pv[4 * a4i + 0] = v.x; pv[4 * a4i + 1] = v.y;
        pv[4 * a4i + 2] = v.z; pv[4 * a4i + 3] = v.w;
    }
    float vmax = -INFINITY;
    #pragma unroll
    for (int a = 0; a < 16; ++a) vmax = fmaxf(vmax, pv[a]);
    float mold_ij = 0.f, mold_ji = 0.f;

    for (int t = 0; t < NITERS; ++t) {
        const float* uSo = Sbuf + t * 32000;
        float* uSn = Sbuf + (t + 1) * 32000;
        const float bi = uSo[gi2 * 16 + L] - mold_ij;
        const float bj = uSo[gj2 * 16 + L] - mold_ji;
        float mj = -INFINITY;
        #pragma unroll
        for (int a = 0; a < 16; ++a)
            mj = fmaxf(mj, pv[a] + __shfl(bi, a, 16));
        float mi = vmax + bj;
        float sj = mj, si = mi;
        #pragma unroll
        for (int off = 1; off < 16; off <<= 1) {
            sj += __shfl_xor(sj, off, 16);
            si += __shfl_xor(si, off, 16);
        }
        mj -= sj * (1.f / 16.f);
        mi -= si * (1.f / 16.f);
        mold_ji = mj;
        mold_ij = mi;
        if (wf) {
            atomicAdd(&uSn[gj2 * 16 + L], mj);
            atomicAdd(&uSn[gi2 * 16 + L], mi);
        }
        grid_bar(flags, 3 + t);              // Sbuf[t+1] complete
    }

    // ---- node-all: blocks 0..287, one t per 36-block group ----
    if (bid < 288) {
        const int t2 = bid / 36;
        const int r2 = (bid % 36) * 512 + tid;
        const float* Sn = Sbuf + (t2 + 1) * 32000;
        float partial = 0.f;
        if (r2 < N_NODES) {
            int n = r2;
            float bv = Sn[n * 16];
            int best = 0;
            #pragma unroll
            for (int a = 1; a < 16; ++a) {
                float v = Sn[n * 16 + a];
                if (v > bv) { bv = v; best = a; }
            }
            AGST(&aidx[t2 * N_NODES + n], best);
            partial = u_out[n * 16 + best];
        } else if (r2 < N_NODES + NE) {
            int ee = r2 - N_NODES;
            int ii = edges[2 * ee], jj = edges[2 * ee + 1];
            float bvi = Sn[ii * 16]; int ai = 0;
            #pragma unroll
            for (int a = 1; a < 16; ++a) {
                float v = Sn[ii * 16 + a];
                if (v > bvi) { bvi = v; ai = a; }
            }
            float bvj = Sn[jj * 16]; int aj = 0;
            #pragma unroll
            for (int a = 1; a < 16; ++a) {
                float v = Sn[jj * 16 + a];
                if (v > bvj) { bvj = v; aj = a; }
            }
            partial = p_out[ee * 256 + ai * 16 + aj];
        }
        #pragma unroll
        for (int off = 1; off < 64; off <<= 1)
            partial += __shfl_xor(partial, off, 64);
        if ((tid & 63) == 0) atomicAdd(&q[t2], partial);
    }
    grid_bar(flags, NITERS + 3);             // all q[t], aidx final

    // ---- final: running strict-> max over iters, one-hot a ----
    const int r = bid * 512 + tid;
    if (r < N_NODES * 16) {
        float cur = 0.f; int best_t = -1;
        #pragma unroll
        for (int t2 = 0; t2 < NITERS; ++t2) {
            float qv = q[t2];
            if (qv > cur) { cur = qv; best_t = t2; }
        }
        int n = r >> 4, c = r & 15;
        float val = 0.f;
        if (best_t >= 0 && aidx[best_t * N_NODES + n] == c) val = 1.f;
        a_out[r] = val;
        if (r == 0) q_out[0] = cur;
    }
}

extern "C" void kernel_launch(void* const* d_in, const int* in_sizes, int n_in,
                              void* d_out, int out_size, void* d_ws, size_t ws_size,
                              hipStream_t stream)
{
    (void)in_sizes; (void)n_in; (void)out_size; (void)ws_size;
    const float* x    = (const float*)d_in[0];
    const float* pa   = (const float*)d_in[1];
    const float* st   = (const float*)d_in[2];
    const int*   edges= (const int*)d_in[3];
    const float* gwih = (const float*)d_in[4];
    const float* gwhh = (const float*)d_in[5];
    const float* gbih = (const float*)d_in[6];
    const float* gbhh = (const float*)d_in[7];
    const float* uW0 = (const float*)d_in[8];  const float* ub0 = (const float*)d_in[9];
    const float* uW1 = (const float*)d_in[10]; const float* ub1 = (const float*)d_in[11];
    const float* uW2 = (const float*)d_in[12]; const float* ub2 = (const float*)d_in[13];
    const float* pW0 = (const float*)d_in[14]; const float* pb0 = (const float*)d_in[15];
    const float* pW1 = (const float*)d_in[16]; const float* pb1 = (const float*)d_in[17];
    const float* pW2 = (const float*)d_in[18]; const float* pb2 = (const float*)d_in[19];
    const float* pW3 = (const float*)d_in[20]; const float* pb3 = (const float*)d_in[21];
    const float* pW4 = (const float*)d_in[22]; const float* pb4 = (const float*)d_in[23];

    float* out   = (float*)d_out;
    float* a_out = out;                 // 32000
    float* q_out = out + 32000;         // 1
    float* u_out = out + 32001;         // 32000
    float* p_out = out + 64001;         // 4,096,000
    float* h_out = out + 4160001;       // 256,000 (state_out)

    float* ws = (float*)d_ws;

    setup_kernel<<<1399, 256, 0, stream>>>(ws, edges, uW0, uW1, uW2,
                                           pW0, pW1, pW2, pW3, pW4, gwih, gwhh);
    mega_kernel<<<NBLK, 512, 0, stream>>>(x, pa, st, gbih, gbhh,
                                          ub0, ub1, ub2,
                                          pb0, pb1, pb2, pb3, pb4,
                                          edges, ws, h_out, u_out, p_out,
                                          a_out, q_out);
}